// Round 5
// baseline (512.219 us; speedup 1.0000x reference)
//
#include <hip/hip_runtime.h>
#include <math.h>

#define N_NODES 10000
#define N_EDGES 80000
#define ET (N_EDGES + N_NODES)   // 90000 edges incl. self-loops
#define IN_FEAT 200
#define HID 400
#define NH1 8
#define F1 (NH1 * HID)           // 3200
#define OUT_FEAT 200
#define NEG_SLOPE 0.2f

#define M_PAD 10048              // 157 * 64
#define K1 224                   // per-head K pad (200 -> 224 = 7*32)
#define HSL (NH1 * K1)           // 1792 bf16 per node in xagg
#define XH_K 416                 // per-head hidden K pad (400 -> 416 = 13*32)
#define C1P 416                  // W1bt col pad (400 -> 416)
#define KALL (NH1 * XH_K)        // 3328 = fused K for gemm2 B layout
#define N2P2 256                 // W2bt row pad (cols of h2)

typedef __attribute__((ext_vector_type(8))) short short8_t;
typedef __attribute__((ext_vector_type(4))) float f32x4;

// swizzled LDS index (ushort units); row stride 512, XOR bits 3..5 by row&7
#define SWI(r, c) ((r) * 512 + ((c) ^ (((r) & 7) << 3)))

// ---------- helpers ----------

__device__ inline void edge_sd(const int* __restrict__ ei, int e, int& s, int& d) {
    if (e < N_EDGES) { s = ei[e]; d = ei[N_EDGES + e]; }
    else { s = e - N_EDGES; d = s; }
}

__device__ inline void atomicMaxF(float* addr, float val) {
    if (val >= 0.f) atomicMax((int*)addr, __float_as_int(val));
    else            atomicMin((unsigned int*)addr, (unsigned int)__float_as_uint(val));
}

__device__ inline unsigned short f2bf(float x) {
    unsigned u = __float_as_uint(x);
    unsigned r = u + 0x7FFFu + ((u >> 16) & 1u);
    return (unsigned short)(r >> 16);
}

// ---------- init ----------
__global__ __launch_bounds__(256) void init_k(float* __restrict__ emax1, float* __restrict__ den1,
                                              float* __restrict__ emax2, float* __restrict__ den2,
                                              int* __restrict__ counts, int* __restrict__ cursor) {
    int i = blockIdx.x * blockDim.x + threadIdx.x;
    if (i < N_NODES * NH1) { emax1[i] = -INFINITY; den1[i] = 0.f; }
    if (i < N_NODES) { emax2[i] = -INFINITY; den2[i] = 0.f; counts[i] = 0; cursor[i] = 0; }
}

// ---------- weight prep: W1bt[h][c<416][k<224] bf16, zero-padded both dims ----------
__global__ __launch_bounds__(256) void prep_w1(const float* __restrict__ W1,
                                               unsigned short* __restrict__ W1bt) {
    int idx = blockIdx.x * blockDim.x + threadIdx.x;
    if (idx >= NH1 * C1P * K1) return;
    int h = idx / (C1P * K1);
    int rem = idx - h * (C1P * K1);
    int c = rem / K1, k = rem - c * K1;
    float v = (k < IN_FEAT && c < HID) ? W1[(size_t)k * F1 + h * HID + c] : 0.f;
    W1bt[idx] = f2bf(v);
}

// ---------- weight prep: W2bt[c<256][h*416+k1] bf16, zero-padded ----------
__global__ __launch_bounds__(256) void prep_w2(const float* __restrict__ W2,
                                               unsigned short* __restrict__ W2bt) {
    int idx = blockIdx.x * blockDim.x + threadIdx.x;
    if (idx >= N2P2 * KALL) return;
    int c = idx / KALL;
    int rem = idx - c * KALL;
    int h = rem / XH_K, k1 = rem - h * XH_K;
    float v = (c < OUT_FEAT && k1 < HID) ? W2[(size_t)(h * HID + k1) * OUT_FEAT + c] : 0.f;
    W2bt[idx] = f2bf(v);
}

// ---------- p-vectors ----------
__global__ __launch_bounds__(256) void pvec_k(const float* __restrict__ W1,
                                              const float* __restrict__ a_src,
                                              const float* __restrict__ a_dst,
                                              float* __restrict__ p_src,
                                              float* __restrict__ p_dst) {
    int idx = blockIdx.x * blockDim.x + threadIdx.x;
    if (idx >= 2 * NH1 * IN_FEAT) return;
    int which = idx / (NH1 * IN_FEAT);
    int r = idx - which * (NH1 * IN_FEAT);
    int h = r / IN_FEAT, k = r - h * IN_FEAT;
    const float* av = (which == 0 ? a_src : a_dst) + h * HID;
    const float* wrow = W1 + (size_t)k * F1 + h * HID;
    float acc = 0.f;
    for (int c = 0; c < HID; ++c) acc += wrow[c] * av[c];
    (which == 0 ? p_src : p_dst)[h * IN_FEAT + k] = acc;
}

// ---------- attention logits layer 1 ----------
__global__ __launch_bounds__(512) void att1x(const float* __restrict__ X,
                                             const float* __restrict__ p_src,
                                             const float* __restrict__ p_dst,
                                             float* __restrict__ als,
                                             float* __restrict__ ald) {
    const int n    = blockIdx.x;
    const int head = threadIdx.x >> 6;
    const int lane = threadIdx.x & 63;
    const float* xp = X + (size_t)n * IN_FEAT;
    const float* ps = p_src + head * IN_FEAT;
    const float* pd = p_dst + head * IN_FEAT;
    float ss = 0.f, sd = 0.f;
    for (int k = lane; k < IN_FEAT; k += 64) {
        float v = xp[k];
        ss += v * ps[k];
        sd += v * pd[k];
    }
    for (int off = 32; off; off >>= 1) {
        ss += __shfl_down(ss, off);
        sd += __shfl_down(sd, off);
    }
    if (lane == 0) { als[n * NH1 + head] = ss; ald[n * NH1 + head] = sd; }
}

// ---------- attention logits layer 2 ----------
__global__ __launch_bounds__(64) void att2k(const float* __restrict__ Hh,
                                            const float* __restrict__ a_src,
                                            const float* __restrict__ a_dst,
                                            float* __restrict__ als,
                                            float* __restrict__ ald) {
    const int n    = blockIdx.x;
    const int lane = threadIdx.x;
    const float* hp = Hh + (size_t)n * OUT_FEAT;
    float ss = 0.f, sd = 0.f;
    for (int c = lane; c < OUT_FEAT; c += 64) {
        float v = hp[c];
        ss += v * a_src[c];
        sd += v * a_dst[c];
    }
    for (int off = 32; off; off >>= 1) {
        ss += __shfl_down(ss, off);
        sd += __shfl_down(sd, off);
    }
    if (lane == 0) { als[n] = ss; ald[n] = sd; }
}

// ---------- CSR build ----------
__global__ __launch_bounds__(256) void count_k(const int* __restrict__ ei, int* __restrict__ counts) {
    int e = blockIdx.x * blockDim.x + threadIdx.x;
    if (e >= ET) return;
    int s, d; edge_sd(ei, e, s, d);
    atomicAdd(&counts[d], 1);
}

__global__ __launch_bounds__(1024) void scan_k(const int* __restrict__ counts, int* __restrict__ offs) {
    __shared__ int part[1024];
    const int tid = threadIdx.x;
    const int base = tid * 10;
    int loc[10];
    int s = 0;
    for (int i = 0; i < 10; ++i) {
        int idx = base + i;
        int c = (idx < N_NODES) ? counts[idx] : 0;
        loc[i] = s; s += c;
    }
    part[tid] = s;
    __syncthreads();
    for (int off = 1; off < 1024; off <<= 1) {
        int v = (tid >= off) ? part[tid - off] : 0;
        __syncthreads();
        part[tid] += v;
        __syncthreads();
    }
    int pre = (tid > 0) ? part[tid - 1] : 0;
    for (int i = 0; i < 10; ++i) {
        int idx = base + i;
        if (idx < N_NODES) offs[idx] = pre + loc[i];
    }
    if (tid == 1023) offs[N_NODES] = part[1023];
}

__global__ __launch_bounds__(256) void scatter_k(const int* __restrict__ ei,
                                                 const int* __restrict__ offs,
                                                 int* __restrict__ cursor,
                                                 int* __restrict__ esrc) {
    int e = blockIdx.x * blockDim.x + threadIdx.x;
    if (e >= ET) return;
    int s, d; edge_sd(ei, e, s, d);
    int pos = atomicAdd(&cursor[d], 1);
    esrc[offs[d] + pos] = s;
}

// ---------- edge softmax stats ----------
template <int H>
__global__ __launch_bounds__(256) void edge_max_k(const int* __restrict__ ei,
                                                  const float* __restrict__ als,
                                                  const float* __restrict__ ald,
                                                  float* __restrict__ emax) {
    int idx = blockIdx.x * blockDim.x + threadIdx.x;
    if (idx >= ET * H) return;
    int e = idx / H, h = idx - e * H;
    int s, d; edge_sd(ei, e, s, d);
    float v = als[s * H + h] + ald[d * H + h];
    v = v > 0.f ? v : NEG_SLOPE * v;
    atomicMaxF(&emax[d * H + h], v);
}

template <int H>
__global__ __launch_bounds__(256) void edge_den_k(const int* __restrict__ ei,
                                                  const float* __restrict__ als,
                                                  const float* __restrict__ ald,
                                                  const float* __restrict__ emax,
                                                  float* __restrict__ den) {
    int idx = blockIdx.x * blockDim.x + threadIdx.x;
    if (idx >= ET * H) return;
    int e = idx / H, h = idx - e * H;
    int s, d; edge_sd(ei, e, s, d);
    float v = als[s * H + h] + ald[d * H + h];
    v = v > 0.f ? v : NEG_SLOPE * v;
    unsafeAtomicAdd(&den[d * H + h], __expf(v - emax[d * H + h]));
}

// ---------- Stage A: xagg[n,h,0:224] (bf16) ----------
__global__ __launch_bounds__(512) void agg1x(const float* __restrict__ X,
                                             const float* __restrict__ als1,
                                             const float* __restrict__ ald1,
                                             const float* __restrict__ emax1,
                                             const float* __restrict__ den1,
                                             const int* __restrict__ offs,
                                             const int* __restrict__ esrc,
                                             unsigned short* __restrict__ xaggb) {
    __shared__ unsigned short sb[8][HSL];   // 28672 B
    const int wave = threadIdx.x >> 6;
    const int lane = threadIdx.x & 63;
    const int n = blockIdx.x * 8 + wave;

    if (n < N_NODES) {
        float acc[NH1][4];
#pragma unroll
        for (int h = 0; h < NH1; ++h)
#pragma unroll
            for (int g = 0; g < 4; ++g) acc[h][g] = 0.f;

        float aldv = 0.f, em = 0.f, dn = 1.f;
        if (lane < NH1) {
            aldv = ald1[n * NH1 + lane];
            em   = emax1[n * NH1 + lane];
            dn   = den1[n * NH1 + lane];
        }
        const int beg = offs[n], end = offs[n + 1];
        for (int t = beg; t < end; ++t) {
            const int s = esrc[t];
            float aval = 0.f;
            if (lane < NH1) {
                float v = als1[s * NH1 + lane] + aldv;
                v = v > 0.f ? v : NEG_SLOPE * v;
                aval = __expf(v - em) / dn;
            }
            const float* xp = X + (size_t)s * IN_FEAT;
            float x0 = xp[lane];
            float x1 = xp[64 + lane];
            float x2 = xp[128 + lane];
            float x3 = (lane < 8) ? xp[192 + lane] : 0.f;
#pragma unroll
            for (int h = 0; h < NH1; ++h) {
                float a = __shfl(aval, h);
                acc[h][0] += a * x0;
                acc[h][1] += a * x1;
                acc[h][2] += a * x2;
                acc[h][3] += a * x3;
            }
        }
#pragma unroll
        for (int h = 0; h < NH1; ++h) {
            sb[wave][h * K1 + lane]        = f2bf(acc[h][0]);
            sb[wave][h * K1 + 64 + lane]   = f2bf(acc[h][1]);
            sb[wave][h * K1 + 128 + lane]  = f2bf(acc[h][2]);
            if (lane < 32) {
                unsigned short v3 = (lane < 8) ? f2bf(acc[h][3]) : (unsigned short)0;
                sb[wave][h * K1 + 192 + lane] = v3;
            }
        }
    } else {
        for (int j = lane; j < HSL; j += 64) sb[wave][j] = 0;
    }
    __syncthreads();
    const uint4* s4 = (const uint4*)(&sb[0][0]);
    uint4* d4 = (uint4*)(xaggb + (size_t)blockIdx.x * 8 * HSL);
    for (int c = threadIdx.x; c < 8 * HSL / 8; c += 512) d4[c] = s4[c];
}

// ---------- fused GEMM1+GEMM2: per 32-row tile, per head: xh in LDS, h2 += ----------
// grid (M_PAD/32, 2); block 256 = 4 waves.
// wave w: rows r0=(w&1)*16; gemm1 cols c0=(w>>1)*208 (13 frags); gemm2 cols c2=(w>>1)*112 (7 frags)
__global__ __launch_bounds__(256) void fused_gemm(const unsigned short* __restrict__ xaggb,
                                                  const unsigned short* __restrict__ W1bt,
                                                  const float* __restrict__ b1,
                                                  const unsigned short* __restrict__ W2bt,
                                                  float* __restrict__ h2) {
    __shared__ unsigned short xhf[32 * 512];   // 32 KB, swizzled
    const int wave = threadIdx.x >> 6;
    const int lane = threadIdx.x & 63;
    const int row  = lane & 15;
    const int kg   = lane >> 4;
    const int m0   = blockIdx.x * 32;
    const int r0   = (wave & 1) * 16;
    const int c0   = (wave >> 1) * 208;
    const int c2   = (wave >> 1) * 112;

    f32x4 oacc[7];
#pragma unroll
    for (int j = 0; j < 7; ++j) oacc[j] = (f32x4){0.f, 0.f, 0.f, 0.f};

    for (int hh = 0; hh < 4; ++hh) {
        const int h = blockIdx.y * 4 + hh;

        // ---- gemm1: acc[j] = xagg_h[16 rows] @ W1_h[208 cols] ----
        const unsigned short* ap = xaggb + (size_t)(m0 + r0 + row) * HSL + h * K1 + kg * 8;
        const unsigned short* bp = W1bt + ((size_t)h * C1P + c0 + row) * K1 + kg * 8;
        f32x4 acc[13];
#pragma unroll
        for (int j = 0; j < 13; ++j) acc[j] = (f32x4){0.f, 0.f, 0.f, 0.f};
        for (int ks = 0; ks < 7; ++ks) {
            short8_t a = *(const short8_t*)(ap + ks * 32);
#pragma unroll
            for (int j = 0; j < 13; ++j) {
                short8_t b = *(const short8_t*)(bp + (size_t)j * 16 * K1 + ks * 32);
                acc[j] = __builtin_amdgcn_mfma_f32_16x16x32_bf16(a, b, acc[j], 0, 0, 0);
            }
        }

        if (hh > 0) __syncthreads();   // previous head's LDS reads complete

        // ---- bias + ELU -> swizzled LDS ----
#pragma unroll
        for (int j = 0; j < 13; ++j) {
            int cc = c0 + j * 16 + row;
            float bias = (cc < HID) ? b1[h * HID + cc] : 0.f;
#pragma unroll
            for (int r = 0; r < 4; ++r) {
                int rl = r0 + kg * 4 + r;
                float v = acc[j][r] + bias;
                v = v > 0.f ? v : (__expf(v) - 1.f);
                xhf[SWI(rl, cc)] = f2bf(v);
            }
        }
        __syncthreads();

        // ---- gemm2: oacc += xh[16 rows x 416] @ W2_h[112 cols] ----
        const unsigned short* bp2 = W2bt + (size_t)(c2 + row) * KALL + h * XH_K + kg * 8;
        const int rl = r0 + row;
        for (int ks = 0; ks < 13; ++ks) {
            short8_t a = *(const short8_t*)&xhf[SWI(rl, kg * 8 + ks * 32)];
#pragma unroll
            for (int j = 0; j < 7; ++j) {
                short8_t b = *(const short8_t*)(bp2 + (size_t)j * 16 * KALL + ks * 32);
                oacc[j] = __builtin_amdgcn_mfma_f32_16x16x32_bf16(a, b, oacc[j], 0, 0, 0);
            }
        }
    }

    // ---- write h2 (two y-blocks combine via atomics) ----
#pragma unroll
    for (int j = 0; j < 7; ++j) {
        int cc = c2 + j * 16 + row;
        if (cc < OUT_FEAT) {
#pragma unroll
            for (int r = 0; r < 4; ++r) {
                int rr = m0 + r0 + kg * 4 + r;
                if (rr < N_NODES)
                    unsafeAtomicAdd(&h2[(size_t)rr * OUT_FEAT + cc], oacc[j][r]);
            }
        }
    }
}

// ---------- layer-2 aggregation ----------
__global__ __launch_bounds__(256) void agg2_csr(const float* __restrict__ h2,
                                                const float* __restrict__ als2,
                                                const float* __restrict__ ald2,
                                                const float* __restrict__ emax2,
                                                const float* __restrict__ den2,
                                                const int* __restrict__ offs,
                                                const int* __restrict__ esrc,
                                                const float* __restrict__ b2,
                                                float* __restrict__ out) {
    const int n = blockIdx.x;
    const int k = threadIdx.x;
    if (k >= OUT_FEAT) return;
    const float aldn = ald2[n], em = emax2[n], dn = den2[n];
    const int beg = offs[n], end = offs[n + 1];
    float acc = 0.f;
    for (int t = beg; t < end; ++t) {
        int s = esrc[t];
        float v = als2[s] + aldn;
        v = v > 0.f ? v : NEG_SLOPE * v;
        float a = __expf(v - em) / dn;
        acc += a * h2[(size_t)s * OUT_FEAT + k];
    }
    out[(size_t)n * OUT_FEAT + k] = acc + b2[k];
}

// ---------- launch ----------
extern "C" void kernel_launch(void* const* d_in, const int* in_sizes, int n_in,
                              void* d_out, int out_size, void* d_ws, size_t ws_size,
                              hipStream_t stream) {
    const float* X   = (const float*)d_in[0];
    const int*   ei  = (const int*)d_in[1];
    const float* W1  = (const float*)d_in[2];
    const float* as1 = (const float*)d_in[3];
    const float* ad1 = (const float*)d_in[4];
    const float* b1  = (const float*)d_in[5];
    const float* W2  = (const float*)d_in[6];
    const float* as2 = (const float*)d_in[7];
    const float* ad2 = (const float*)d_in[8];
    const float* b2  = (const float*)d_in[9];
    float* out = (float*)d_out;

    char* base = (char*)d_ws;
    auto carve = [&](size_t bytes) -> void* {
        void* p = (void*)base;
        base += (bytes + 255) & ~(size_t)255;
        return p;
    };
    float* p_src1 = (float*)carve(NH1 * IN_FEAT * 4);
    float* p_dst1 = (float*)carve(NH1 * IN_FEAT * 4);
    float* als1   = (float*)carve(N_NODES * NH1 * 4);
    float* ald1   = (float*)carve(N_NODES * NH1 * 4);
    float* emax1  = (float*)carve(N_NODES * NH1 * 4);
    float* den1   = (float*)carve(N_NODES * NH1 * 4);
    float* als2   = (float*)carve(N_NODES * 4);
    float* ald2   = (float*)carve(N_NODES * 4);
    float* emax2  = (float*)carve(N_NODES * 4);
    float* den2   = (float*)carve(N_NODES * 4);
    float* h2     = (float*)carve((size_t)N_NODES * OUT_FEAT * 4);
    int* counts   = (int*)carve(N_NODES * 4);
    int* cursor   = (int*)carve(N_NODES * 4);
    int* offs     = (int*)carve((N_NODES + 1) * 4);
    int* esrc     = (int*)carve(ET * 4);
    unsigned short* xaggb = (unsigned short*)carve((size_t)M_PAD * HSL * 2);      // 36 MB
    unsigned short* W1bt  = (unsigned short*)carve((size_t)NH1 * C1P * K1 * 2);   // 1.5 MB
    unsigned short* W2bt  = (unsigned short*)carve((size_t)N2P2 * KALL * 2);      // 1.7 MB

    // per-call init (harness does not re-poison between replays)
    init_k<<<(N_NODES * NH1 + 255) / 256, 256, 0, stream>>>(emax1, den1, emax2, den2, counts, cursor);
    hipMemsetAsync(h2, 0, (size_t)N_NODES * OUT_FEAT * 4, stream);

    // CSR + weight prep + logits
    count_k<<<(ET + 255) / 256, 256, 0, stream>>>(ei, counts);
    scan_k<<<1, 1024, 0, stream>>>(counts, offs);
    scatter_k<<<(ET + 255) / 256, 256, 0, stream>>>(ei, offs, cursor, esrc);
    prep_w1<<<(NH1 * C1P * K1 + 255) / 256, 256, 0, stream>>>(W1, W1bt);
    prep_w2<<<(N2P2 * KALL + 255) / 256, 256, 0, stream>>>(W2, W2bt);
    pvec_k<<<(2 * NH1 * IN_FEAT + 255) / 256, 256, 0, stream>>>(W1, as1, ad1, p_src1, p_dst1);
    att1x<<<N_NODES, 512, 0, stream>>>(X, p_src1, p_dst1, als1, ald1);
    edge_max_k<NH1><<<(ET * NH1 + 255) / 256, 256, 0, stream>>>(ei, als1, ald1, emax1);
    edge_den_k<NH1><<<(ET * NH1 + 255) / 256, 256, 0, stream>>>(ei, als1, ald1, emax1, den1);

    // Stage A: aggregated features (bf16, padded)
    agg1x<<<M_PAD / 8, 512, 0, stream>>>(X, als1, ald1, emax1, den1, offs, esrc, xaggb);

    // fused GEMM1 (+bias+ELU) + GEMM2, xh stays in LDS
    fused_gemm<<<dim3(M_PAD / 32, 2), 256, 0, stream>>>(xaggb, W1bt, b1, W2bt, h2);

    // layer 2 softmax + aggregation (fp32)
    att2k<<<N_NODES, 64, 0, stream>>>(h2, as2, ad2, als2, ald2);
    edge_max_k<1><<<(ET + 255) / 256, 256, 0, stream>>>(ei, als2, ald2, emax2);
    edge_den_k<1><<<(ET + 255) / 256, 256, 0, stream>>>(ei, als2, ald2, emax2, den2);
    agg2_csr<<<N_NODES, 256, 0, stream>>>(h2, als2, ald2, emax2, den2, offs, esrc, b2, out);
}

// Round 6
// 381.415 us; speedup vs baseline: 1.3429x; 1.3429x over previous
//
#include <hip/hip_runtime.h>
#include <math.h>

#define N_NODES 10000
#define N_EDGES 80000
#define ET (N_EDGES + N_NODES)   // 90000 edges incl. self-loops
#define IN_FEAT 200
#define HID 400
#define NH1 8
#define F1 (NH1 * HID)           // 3200
#define OUT_FEAT 200
#define NEG_SLOPE 0.2f

#define M_PAD 10048              // 157 * 64
#define K1 224                   // per-head K pad (200 -> 224 = 7*32)
#define HSL (NH1 * K1)           // 1792 bf16 per node in xagg
#define XH_K 416                 // per-head hidden K pad (400 -> 416 = 13*32)
#define C1P 416                  // W1bt col pad (400 -> 416)
#define KALL (NH1 * XH_K)        // 3328 = fused K for gemm2 B layout
#define N2P2 256                 // W2bt row pad (cols of h2)
#define XHS 424                  // LDS xh row stride (ushorts): bank step 20 -> conflict-free-ish

typedef __attribute__((ext_vector_type(8))) short short8_t;
typedef __attribute__((ext_vector_type(4))) float f32x4;

// ---------- helpers ----------

__device__ inline void edge_sd(const int* __restrict__ ei, int e, int& s, int& d) {
    if (e < N_EDGES) { s = ei[e]; d = ei[N_EDGES + e]; }
    else { s = e - N_EDGES; d = s; }
}

__device__ inline void atomicMaxF(float* addr, float val) {
    if (val >= 0.f) atomicMax((int*)addr, __float_as_int(val));
    else            atomicMin((unsigned int*)addr, (unsigned int)__float_as_uint(val));
}

__device__ inline unsigned short f2bf(float x) {
    unsigned u = __float_as_uint(x);
    unsigned r = u + 0x7FFFu + ((u >> 16) & 1u);
    return (unsigned short)(r >> 16);
}

// ---------- init ----------
__global__ __launch_bounds__(256) void init_k(float* __restrict__ emax1, float* __restrict__ den1,
                                              float* __restrict__ emax2, float* __restrict__ den2,
                                              int* __restrict__ counts, int* __restrict__ cursor) {
    int i = blockIdx.x * blockDim.x + threadIdx.x;
    if (i < N_NODES * NH1) { emax1[i] = -INFINITY; den1[i] = 0.f; }
    if (i < N_NODES) { emax2[i] = -INFINITY; den2[i] = 0.f; counts[i] = 0; cursor[i] = 0; }
}

// ---------- weight prep (merged): W1bt[h][c<416][k<224], W2bt[c<256][h*416+k1] ----------
#define W1N (NH1 * C1P * K1)     // 745472
#define W2N (N2P2 * KALL)        // 851968
__global__ __launch_bounds__(256) void prep_w(const float* __restrict__ W1,
                                              const float* __restrict__ W2,
                                              unsigned short* __restrict__ W1bt,
                                              unsigned short* __restrict__ W2bt) {
    int idx = blockIdx.x * blockDim.x + threadIdx.x;
    if (idx < W1N) {
        int h = idx / (C1P * K1);
        int rem = idx - h * (C1P * K1);
        int c = rem / K1, k = rem - c * K1;
        float v = (k < IN_FEAT && c < HID) ? W1[(size_t)k * F1 + h * HID + c] : 0.f;
        W1bt[idx] = f2bf(v);
    } else if (idx < W1N + W2N) {
        int i2 = idx - W1N;
        int c = i2 / KALL;
        int rem = i2 - c * KALL;
        int h = rem / XH_K, k1 = rem - h * XH_K;
        float v = (c < OUT_FEAT && k1 < HID) ? W2[(size_t)(h * HID + k1) * OUT_FEAT + c] : 0.f;
        W2bt[i2] = f2bf(v);
    }
}

// ---------- p-vectors ----------
__global__ __launch_bounds__(256) void pvec_k(const float* __restrict__ W1,
                                              const float* __restrict__ a_src,
                                              const float* __restrict__ a_dst,
                                              float* __restrict__ p_src,
                                              float* __restrict__ p_dst) {
    int idx = blockIdx.x * blockDim.x + threadIdx.x;
    if (idx >= 2 * NH1 * IN_FEAT) return;
    int which = idx / (NH1 * IN_FEAT);
    int r = idx - which * (NH1 * IN_FEAT);
    int h = r / IN_FEAT, k = r - h * IN_FEAT;
    const float* av = (which == 0 ? a_src : a_dst) + h * HID;
    const float* wrow = W1 + (size_t)k * F1 + h * HID;
    float acc = 0.f;
    for (int c = 0; c < HID; ++c) acc += wrow[c] * av[c];
    (which == 0 ? p_src : p_dst)[h * IN_FEAT + k] = acc;
}

// ---------- attention logits layer 1 ----------
__global__ __launch_bounds__(512) void att1x(const float* __restrict__ X,
                                             const float* __restrict__ p_src,
                                             const float* __restrict__ p_dst,
                                             float* __restrict__ als,
                                             float* __restrict__ ald) {
    const int n    = blockIdx.x;
    const int head = threadIdx.x >> 6;
    const int lane = threadIdx.x & 63;
    const float* xp = X + (size_t)n * IN_FEAT;
    const float* ps = p_src + head * IN_FEAT;
    const float* pd = p_dst + head * IN_FEAT;
    float ss = 0.f, sd = 0.f;
    for (int k = lane; k < IN_FEAT; k += 64) {
        float v = xp[k];
        ss += v * ps[k];
        sd += v * pd[k];
    }
    for (int off = 32; off; off >>= 1) {
        ss += __shfl_down(ss, off);
        sd += __shfl_down(sd, off);
    }
    if (lane == 0) { als[n * NH1 + head] = ss; ald[n * NH1 + head] = sd; }
}

// ---------- attention logits layer 2 ----------
__global__ __launch_bounds__(64) void att2k(const float* __restrict__ Hh,
                                            const float* __restrict__ a_src,
                                            const float* __restrict__ a_dst,
                                            float* __restrict__ als,
                                            float* __restrict__ ald) {
    const int n    = blockIdx.x;
    const int lane = threadIdx.x;
    const float* hp = Hh + (size_t)n * OUT_FEAT;
    float ss = 0.f, sd = 0.f;
    for (int c = lane; c < OUT_FEAT; c += 64) {
        float v = hp[c];
        ss += v * a_src[c];
        sd += v * a_dst[c];
    }
    for (int off = 32; off; off >>= 1) {
        ss += __shfl_down(ss, off);
        sd += __shfl_down(sd, off);
    }
    if (lane == 0) { als[n] = ss; ald[n] = sd; }
}

// ---------- CSR build ----------
__global__ __launch_bounds__(256) void count_k(const int* __restrict__ ei, int* __restrict__ counts) {
    int e = blockIdx.x * blockDim.x + threadIdx.x;
    if (e >= ET) return;
    int s, d; edge_sd(ei, e, s, d);
    atomicAdd(&counts[d], 1);
}

__global__ __launch_bounds__(1024) void scan_k(const int* __restrict__ counts, int* __restrict__ offs) {
    __shared__ int part[1024];
    const int tid = threadIdx.x;
    const int base = tid * 10;
    int loc[10];
    int s = 0;
    for (int i = 0; i < 10; ++i) {
        int idx = base + i;
        int c = (idx < N_NODES) ? counts[idx] : 0;
        loc[i] = s; s += c;
    }
    part[tid] = s;
    __syncthreads();
    for (int off = 1; off < 1024; off <<= 1) {
        int v = (tid >= off) ? part[tid - off] : 0;
        __syncthreads();
        part[tid] += v;
        __syncthreads();
    }
    int pre = (tid > 0) ? part[tid - 1] : 0;
    for (int i = 0; i < 10; ++i) {
        int idx = base + i;
        if (idx < N_NODES) offs[idx] = pre + loc[i];
    }
    if (tid == 1023) offs[N_NODES] = part[1023];
}

__global__ __launch_bounds__(256) void scatter_k(const int* __restrict__ ei,
                                                 const int* __restrict__ offs,
                                                 int* __restrict__ cursor,
                                                 int* __restrict__ esrc) {
    int e = blockIdx.x * blockDim.x + threadIdx.x;
    if (e >= ET) return;
    int s, d; edge_sd(ei, e, s, d);
    int pos = atomicAdd(&cursor[d], 1);
    esrc[offs[d] + pos] = s;
}

// ---------- edge softmax stats ----------
template <int H>
__global__ __launch_bounds__(256) void edge_max_k(const int* __restrict__ ei,
                                                  const float* __restrict__ als,
                                                  const float* __restrict__ ald,
                                                  float* __restrict__ emax) {
    int idx = blockIdx.x * blockDim.x + threadIdx.x;
    if (idx >= ET * H) return;
    int e = idx / H, h = idx - e * H;
    int s, d; edge_sd(ei, e, s, d);
    float v = als[s * H + h] + ald[d * H + h];
    v = v > 0.f ? v : NEG_SLOPE * v;
    atomicMaxF(&emax[d * H + h], v);
}

template <int H>
__global__ __launch_bounds__(256) void edge_den_k(const int* __restrict__ ei,
                                                  const float* __restrict__ als,
                                                  const float* __restrict__ ald,
                                                  const float* __restrict__ emax,
                                                  float* __restrict__ den) {
    int idx = blockIdx.x * blockDim.x + threadIdx.x;
    if (idx >= ET * H) return;
    int e = idx / H, h = idx - e * H;
    int s, d; edge_sd(ei, e, s, d);
    float v = als[s * H + h] + ald[d * H + h];
    v = v > 0.f ? v : NEG_SLOPE * v;
    unsafeAtomicAdd(&den[d * H + h], __expf(v - emax[d * H + h]));
}

// ---------- Stage A: xagg[n,h,0:224] (bf16) ----------
__global__ __launch_bounds__(512) void agg1x(const float* __restrict__ X,
                                             const float* __restrict__ als1,
                                             const float* __restrict__ ald1,
                                             const float* __restrict__ emax1,
                                             const float* __restrict__ den1,
                                             const int* __restrict__ offs,
                                             const int* __restrict__ esrc,
                                             unsigned short* __restrict__ xaggb) {
    __shared__ unsigned short sb[8][HSL];   // 28672 B
    const int wave = threadIdx.x >> 6;
    const int lane = threadIdx.x & 63;
    const int n = blockIdx.x * 8 + wave;

    if (n < N_NODES) {
        float acc[NH1][4];
#pragma unroll
        for (int h = 0; h < NH1; ++h)
#pragma unroll
            for (int g = 0; g < 4; ++g) acc[h][g] = 0.f;

        float aldv = 0.f, em = 0.f, dn = 1.f;
        if (lane < NH1) {
            aldv = ald1[n * NH1 + lane];
            em   = emax1[n * NH1 + lane];
            dn   = den1[n * NH1 + lane];
        }
        const int beg = offs[n], end = offs[n + 1];
        for (int t = beg; t < end; ++t) {
            const int s = esrc[t];
            float aval = 0.f;
            if (lane < NH1) {
                float v = als1[s * NH1 + lane] + aldv;
                v = v > 0.f ? v : NEG_SLOPE * v;
                aval = __expf(v - em) / dn;
            }
            const float* xp = X + (size_t)s * IN_FEAT;
            float x0 = xp[lane];
            float x1 = xp[64 + lane];
            float x2 = xp[128 + lane];
            float x3 = (lane < 8) ? xp[192 + lane] : 0.f;
#pragma unroll
            for (int h = 0; h < NH1; ++h) {
                float a = __shfl(aval, h);
                acc[h][0] += a * x0;
                acc[h][1] += a * x1;
                acc[h][2] += a * x2;
                acc[h][3] += a * x3;
            }
        }
#pragma unroll
        for (int h = 0; h < NH1; ++h) {
            sb[wave][h * K1 + lane]        = f2bf(acc[h][0]);
            sb[wave][h * K1 + 64 + lane]   = f2bf(acc[h][1]);
            sb[wave][h * K1 + 128 + lane]  = f2bf(acc[h][2]);
            if (lane < 32) {
                unsigned short v3 = (lane < 8) ? f2bf(acc[h][3]) : (unsigned short)0;
                sb[wave][h * K1 + 192 + lane] = v3;
            }
        }
    } else {
        for (int j = lane; j < HSL; j += 64) sb[wave][j] = 0;
    }
    __syncthreads();
    const uint4* s4 = (const uint4*)(&sb[0][0]);
    uint4* d4 = (uint4*)(xaggb + (size_t)blockIdx.x * 8 * HSL);
    for (int c = threadIdx.x; c < 8 * HSL / 8; c += 512) d4[c] = s4[c];
}

// ---------- fused GEMM v2: one head per block, 32-row tile, xh in LDS ----------
// grid (M_PAD/32 = 314, NH1 = 8); block 256 = 4 waves; ONE barrier per block.
// wave w: rows r0=(w&1)*16; gemm1 cols c0=(w>>1)*208 (13 frags); gemm2 cols c2=(w>>1)*112 (7 frags)
__global__ __launch_bounds__(256) void fused_gemm(const unsigned short* __restrict__ xaggb,
                                                  const unsigned short* __restrict__ W1bt,
                                                  const float* __restrict__ b1,
                                                  const unsigned short* __restrict__ W2bt,
                                                  float* __restrict__ h2) {
    __shared__ unsigned short xhf[32 * XHS];   // 27.1 KB
    const int wave = threadIdx.x >> 6;
    const int lane = threadIdx.x & 63;
    const int row  = lane & 15;
    const int kg   = lane >> 4;
    const int h    = blockIdx.y;
    const int m0   = blockIdx.x * 32;
    const int r0   = (wave & 1) * 16;
    const int c0   = (wave >> 1) * 208;
    const int c2   = (wave >> 1) * 112;

    // ---- gemm1: acc[j] = xagg_h[16 rows] @ W1_h[208 cols], K=224 ----
    const unsigned short* ap = xaggb + (size_t)(m0 + r0 + row) * HSL + h * K1 + kg * 8;
    const unsigned short* bp = W1bt + ((size_t)h * C1P + c0 + row) * K1 + kg * 8;
    f32x4 acc[13];
#pragma unroll
    for (int j = 0; j < 13; ++j) acc[j] = (f32x4){0.f, 0.f, 0.f, 0.f};
#pragma unroll
    for (int ks = 0; ks < 7; ++ks) {
        short8_t a = *(const short8_t*)(ap + ks * 32);
#pragma unroll
        for (int j = 0; j < 13; ++j) {
            short8_t b = *(const short8_t*)(bp + (size_t)j * 16 * K1 + ks * 32);
            acc[j] = __builtin_amdgcn_mfma_f32_16x16x32_bf16(a, b, acc[j], 0, 0, 0);
        }
    }

    // ---- bias + ELU -> LDS (padded stride) ----
#pragma unroll
    for (int j = 0; j < 13; ++j) {
        int cc = c0 + j * 16 + row;
        float bias = (cc < HID) ? b1[h * HID + cc] : 0.f;
#pragma unroll
        for (int r = 0; r < 4; ++r) {
            int rl = r0 + kg * 4 + r;
            float v = acc[j][r] + bias;
            v = v > 0.f ? v : (__expf(v) - 1.f);
            xhf[rl * XHS + cc] = f2bf(v);
        }
    }
    __syncthreads();

    // ---- gemm2: oacc[j] += xh[16 rows x 416] @ W2_h[112 cols], A from LDS ----
    const unsigned short* bp2 = W2bt + (size_t)(c2 + row) * KALL + h * XH_K + kg * 8;
    const int rl = r0 + row;
    f32x4 oacc[7];
#pragma unroll
    for (int j = 0; j < 7; ++j) oacc[j] = (f32x4){0.f, 0.f, 0.f, 0.f};
#pragma unroll
    for (int ks = 0; ks < 13; ++ks) {
        short8_t a = *(const short8_t*)&xhf[rl * XHS + kg * 8 + ks * 32];
#pragma unroll
        for (int j = 0; j < 7; ++j) {
            short8_t b = *(const short8_t*)(bp2 + (size_t)j * 16 * KALL + ks * 32);
            oacc[j] = __builtin_amdgcn_mfma_f32_16x16x32_bf16(a, b, oacc[j], 0, 0, 0);
        }
    }

    // ---- h2 += partial (8 head-blocks combine via HW fp32 atomics) ----
#pragma unroll
    for (int j = 0; j < 7; ++j) {
        int cc = c2 + j * 16 + row;
        if (cc < OUT_FEAT) {
#pragma unroll
            for (int r = 0; r < 4; ++r) {
                int rr = m0 + r0 + kg * 4 + r;
                if (rr < N_NODES)
                    unsafeAtomicAdd(&h2[(size_t)rr * OUT_FEAT + cc], oacc[j][r]);
            }
        }
    }
}

// ---------- layer-2 aggregation ----------
__global__ __launch_bounds__(256) void agg2_csr(const float* __restrict__ h2,
                                                const float* __restrict__ als2,
                                                const float* __restrict__ ald2,
                                                const float* __restrict__ emax2,
                                                const float* __restrict__ den2,
                                                const int* __restrict__ offs,
                                                const int* __restrict__ esrc,
                                                const float* __restrict__ b2,
                                                float* __restrict__ out) {
    const int n = blockIdx.x;
    const int k = threadIdx.x;
    if (k >= OUT_FEAT) return;
    const float aldn = ald2[n], em = emax2[n], dn = den2[n];
    const int beg = offs[n], end = offs[n + 1];
    float acc = 0.f;
    for (int t = beg; t < end; ++t) {
        int s = esrc[t];
        float v = als2[s] + aldn;
        v = v > 0.f ? v : NEG_SLOPE * v;
        float a = __expf(v - em) / dn;
        acc += a * h2[(size_t)s * OUT_FEAT + k];
    }
    out[(size_t)n * OUT_FEAT + k] = acc + b2[k];
}

// ---------- launch ----------
extern "C" void kernel_launch(void* const* d_in, const int* in_sizes, int n_in,
                              void* d_out, int out_size, void* d_ws, size_t ws_size,
                              hipStream_t stream) {
    const float* X   = (const float*)d_in[0];
    const int*   ei  = (const int*)d_in[1];
    const float* W1  = (const float*)d_in[2];
    const float* as1 = (const float*)d_in[3];
    const float* ad1 = (const float*)d_in[4];
    const float* b1  = (const float*)d_in[5];
    const float* W2  = (const float*)d_in[6];
    const float* as2 = (const float*)d_in[7];
    const float* ad2 = (const float*)d_in[8];
    const float* b2  = (const float*)d_in[9];
    float* out = (float*)d_out;

    char* base = (char*)d_ws;
    auto carve = [&](size_t bytes) -> void* {
        void* p = (void*)base;
        base += (bytes + 255) & ~(size_t)255;
        return p;
    };
    float* p_src1 = (float*)carve(NH1 * IN_FEAT * 4);
    float* p_dst1 = (float*)carve(NH1 * IN_FEAT * 4);
    float* als1   = (float*)carve(N_NODES * NH1 * 4);
    float* ald1   = (float*)carve(N_NODES * NH1 * 4);
    float* emax1  = (float*)carve(N_NODES * NH1 * 4);
    float* den1   = (float*)carve(N_NODES * NH1 * 4);
    float* als2   = (float*)carve(N_NODES * 4);
    float* ald2   = (float*)carve(N_NODES * 4);
    float* emax2  = (float*)carve(N_NODES * 4);
    float* den2   = (float*)carve(N_NODES * 4);
    float* h2     = (float*)carve((size_t)N_NODES * OUT_FEAT * 4);
    int* counts   = (int*)carve(N_NODES * 4);
    int* cursor   = (int*)carve(N_NODES * 4);
    int* offs     = (int*)carve((N_NODES + 1) * 4);
    int* esrc     = (int*)carve(ET * 4);
    unsigned short* xaggb = (unsigned short*)carve((size_t)M_PAD * HSL * 2);      // 36 MB
    unsigned short* W1bt  = (unsigned short*)carve((size_t)NH1 * C1P * K1 * 2);   // 1.5 MB
    unsigned short* W2bt  = (unsigned short*)carve((size_t)N2P2 * KALL * 2);      // 1.7 MB

    // per-call init (harness does not re-poison between replays)
    init_k<<<(N_NODES * NH1 + 255) / 256, 256, 0, stream>>>(emax1, den1, emax2, den2, counts, cursor);
    hipMemsetAsync(h2, 0, (size_t)N_NODES * OUT_FEAT * 4, stream);

    // CSR + weight prep + logits
    count_k<<<(ET + 255) / 256, 256, 0, stream>>>(ei, counts);
    scan_k<<<1, 1024, 0, stream>>>(counts, offs);
    scatter_k<<<(ET + 255) / 256, 256, 0, stream>>>(ei, offs, cursor, esrc);
    prep_w<<<(W1N + W2N + 255) / 256, 256, 0, stream>>>(W1, W2, W1bt, W2bt);
    pvec_k<<<(2 * NH1 * IN_FEAT + 255) / 256, 256, 0, stream>>>(W1, as1, ad1, p_src1, p_dst1);
    att1x<<<N_NODES, 512, 0, stream>>>(X, p_src1, p_dst1, als1, ald1);
    edge_max_k<NH1><<<(ET * NH1 + 255) / 256, 256, 0, stream>>>(ei, als1, ald1, emax1);
    edge_den_k<NH1><<<(ET * NH1 + 255) / 256, 256, 0, stream>>>(ei, als1, ald1, emax1, den1);

    // Stage A: aggregated features (bf16, padded)
    agg1x<<<M_PAD / 8, 512, 0, stream>>>(X, als1, ald1, emax1, den1, offs, esrc, xaggb);

    // fused GEMM1 (+bias+ELU) + GEMM2; one head per block, xh in LDS
    fused_gemm<<<dim3(M_PAD / 32, NH1), 256, 0, stream>>>(xaggb, W1bt, b1, W2bt, h2);

    // layer 2 softmax + aggregation (fp32)
    att2k<<<N_NODES, 64, 0, stream>>>(h2, as2, ad2, als2, ald2);
    edge_max_k<1><<<(ET + 255) / 256, 256, 0, stream>>>(ei, als2, ald2, emax2);
    edge_den_k<1><<<(ET + 255) / 256, 256, 0, stream>>>(ei, als2, ald2, emax2, den2);
    agg2_csr<<<N_NODES, 256, 0, stream>>>(h2, als2, ald2, emax2, den2, offs, esrc, b2, out);
}

// Round 7
// 339.370 us; speedup vs baseline: 1.5093x; 1.1239x over previous
//
#include <hip/hip_runtime.h>
#include <math.h>

#define N_NODES 10000
#define N_EDGES 80000
#define ET (N_EDGES + N_NODES)   // 90000 edges incl. self-loops
#define IN_FEAT 200
#define HID 400
#define NH1 8
#define F1 (NH1 * HID)           // 3200
#define OUT_FEAT 200
#define NEG_SLOPE 0.2f

#define M_PAD 10048              // 157 * 64
#define K1 224                   // per-head K pad (200 -> 224 = 7*32)
#define HSL (NH1 * K1)           // 1792 bf16 per node in xagg
#define XH_K 416                 // per-head hidden K pad (400 -> 416 = 13*32)
#define C1P 416                  // W1bt col pad (400 -> 416)
#define KALL (NH1 * XH_K)        // 3328 = gemm2 B row length
#define N2P2 256                 // W2bt row pad (cols of h2)
#define XHS 424                  // LDS xh row stride (ushorts)

typedef __attribute__((ext_vector_type(8))) short short8_t;
typedef __attribute__((ext_vector_type(4))) float f32x4;

// ---------- helpers ----------

__device__ inline void edge_sd(const int* __restrict__ ei, int e, int& s, int& d) {
    if (e < N_EDGES) { s = ei[e]; d = ei[N_EDGES + e]; }
    else { s = e - N_EDGES; d = s; }
}

__device__ inline unsigned short f2bf(float x) {
    unsigned u = __float_as_uint(x);
    unsigned r = u + 0x7FFFu + ((u >> 16) & 1u);
    return (unsigned short)(r >> 16);
}

// ---------- weight prep (merged): W1bt[h][c<416][k<224], W2bt[c<256][h*416+k1] ----------
#define W1N (NH1 * C1P * K1)     // 745472
#define W2N (N2P2 * KALL)        // 851968
__global__ __launch_bounds__(256) void prep_w(const float* __restrict__ W1,
                                              const float* __restrict__ W2,
                                              unsigned short* __restrict__ W1bt,
                                              unsigned short* __restrict__ W2bt) {
    int idx = blockIdx.x * blockDim.x + threadIdx.x;
    if (idx < W1N) {
        int h = idx / (C1P * K1);
        int rem = idx - h * (C1P * K1);
        int c = rem / K1, k = rem - c * K1;
        float v = (k < IN_FEAT && c < HID) ? W1[(size_t)k * F1 + h * HID + c] : 0.f;
        W1bt[idx] = f2bf(v);
    } else if (idx < W1N + W2N) {
        int i2 = idx - W1N;
        int c = i2 / KALL;
        int rem = i2 - c * KALL;
        int h = rem / XH_K, k1 = rem - h * XH_K;
        float v = (c < OUT_FEAT && k1 < HID) ? W2[(size_t)(h * HID + k1) * OUT_FEAT + c] : 0.f;
        W2bt[i2] = f2bf(v);
    }
}

// ---------- p-vectors ----------
__global__ __launch_bounds__(256) void pvec_k(const float* __restrict__ W1,
                                              const float* __restrict__ a_src,
                                              const float* __restrict__ a_dst,
                                              float* __restrict__ p_src,
                                              float* __restrict__ p_dst) {
    int idx = blockIdx.x * blockDim.x + threadIdx.x;
    if (idx >= 2 * NH1 * IN_FEAT) return;
    int which = idx / (NH1 * IN_FEAT);
    int r = idx - which * (NH1 * IN_FEAT);
    int h = r / IN_FEAT, k = r - h * IN_FEAT;
    const float* av = (which == 0 ? a_src : a_dst) + h * HID;
    const float* wrow = W1 + (size_t)k * F1 + h * HID;
    float acc = 0.f;
    for (int c = 0; c < HID; ++c) acc += wrow[c] * av[c];
    (which == 0 ? p_src : p_dst)[h * IN_FEAT + k] = acc;
}

// ---------- attention logits layer 1 ----------
__global__ __launch_bounds__(512) void att1x(const float* __restrict__ X,
                                             const float* __restrict__ p_src,
                                             const float* __restrict__ p_dst,
                                             float* __restrict__ als,
                                             float* __restrict__ ald) {
    const int n    = blockIdx.x;
    const int head = threadIdx.x >> 6;
    const int lane = threadIdx.x & 63;
    const float* xp = X + (size_t)n * IN_FEAT;
    const float* ps = p_src + head * IN_FEAT;
    const float* pd = p_dst + head * IN_FEAT;
    float ss = 0.f, sd = 0.f;
    for (int k = lane; k < IN_FEAT; k += 64) {
        float v = xp[k];
        ss += v * ps[k];
        sd += v * pd[k];
    }
    for (int off = 32; off; off >>= 1) {
        ss += __shfl_down(ss, off);
        sd += __shfl_down(sd, off);
    }
    if (lane == 0) { als[n * NH1 + head] = ss; ald[n * NH1 + head] = sd; }
}

// ---------- CSR build ----------
__global__ __launch_bounds__(256) void count_k(const int* __restrict__ ei, int* __restrict__ counts) {
    int e = blockIdx.x * blockDim.x + threadIdx.x;
    if (e >= ET) return;
    int s, d; edge_sd(ei, e, s, d);
    atomicAdd(&counts[d], 1);
}

__global__ __launch_bounds__(1024) void scan_k(const int* __restrict__ counts, int* __restrict__ offs) {
    __shared__ int part[1024];
    const int tid = threadIdx.x;
    const int base = tid * 10;
    int loc[10];
    int s = 0;
    for (int i = 0; i < 10; ++i) {
        int idx = base + i;
        int c = (idx < N_NODES) ? counts[idx] : 0;
        loc[i] = s; s += c;
    }
    part[tid] = s;
    __syncthreads();
    for (int off = 1; off < 1024; off <<= 1) {
        int v = (tid >= off) ? part[tid - off] : 0;
        __syncthreads();
        part[tid] += v;
        __syncthreads();
    }
    int pre = (tid > 0) ? part[tid - 1] : 0;
    for (int i = 0; i < 10; ++i) {
        int idx = base + i;
        if (idx < N_NODES) offs[idx] = pre + loc[i];
    }
    if (tid == 1023) offs[N_NODES] = part[1023];
}

__global__ __launch_bounds__(256) void scatter_k(const int* __restrict__ ei,
                                                 const int* __restrict__ offs,
                                                 int* __restrict__ cursor,
                                                 int* __restrict__ esrc) {
    int e = blockIdx.x * blockDim.x + threadIdx.x;
    if (e >= ET) return;
    int s, d; edge_sd(ei, e, s, d);
    int pos = atomicAdd(&cursor[d], 1);
    esrc[offs[d] + pos] = s;
}

// ---------- Stage A: online softmax + aggregation: xagg[n,h,0:224] (bf16) ----------
__global__ __launch_bounds__(512) void agg1x(const float* __restrict__ X,
                                             const float* __restrict__ als1,
                                             const float* __restrict__ ald1,
                                             const int* __restrict__ offs,
                                             const int* __restrict__ esrc,
                                             unsigned short* __restrict__ xaggb) {
    __shared__ unsigned short sb[8][HSL];   // 28672 B
    const int wave = threadIdx.x >> 6;
    const int lane = threadIdx.x & 63;
    const int n = blockIdx.x * 8 + wave;

    if (n < N_NODES) {
        float acc[NH1][4];
#pragma unroll
        for (int h = 0; h < NH1; ++h)
#pragma unroll
            for (int g = 0; g < 4; ++g) acc[h][g] = 0.f;

        const int beg = offs[n], end = offs[n + 1];
        float aldv = 0.f, m = -INFINITY, l = 0.f;
        if (lane < NH1) aldv = ald1[n * NH1 + lane];

        // pass 1: online max + denominator (lanes 0..7 = heads)
        for (int t = beg; t < end; ++t) {
            const int s = esrc[t];
            if (lane < NH1) {
                float v = als1[s * NH1 + lane] + aldv;
                v = v > 0.f ? v : NEG_SLOPE * v;
                float mn = fmaxf(m, v);
                l = l * __expf(m - mn) + __expf(v - mn);
                m = mn;
            }
        }
        const float inv_l = (lane < NH1) ? 1.f / l : 0.f;

        // pass 2: weighted aggregation
        for (int t = beg; t < end; ++t) {
            const int s = esrc[t];
            float aval = 0.f;
            if (lane < NH1) {
                float v = als1[s * NH1 + lane] + aldv;
                v = v > 0.f ? v : NEG_SLOPE * v;
                aval = __expf(v - m) * inv_l;
            }
            const float* xp = X + (size_t)s * IN_FEAT;
            float x0 = xp[lane];
            float x1 = xp[64 + lane];
            float x2 = xp[128 + lane];
            float x3 = (lane < 8) ? xp[192 + lane] : 0.f;
#pragma unroll
            for (int h = 0; h < NH1; ++h) {
                float a = __shfl(aval, h);
                acc[h][0] += a * x0;
                acc[h][1] += a * x1;
                acc[h][2] += a * x2;
                acc[h][3] += a * x3;
            }
        }
#pragma unroll
        for (int h = 0; h < NH1; ++h) {
            sb[wave][h * K1 + lane]        = f2bf(acc[h][0]);
            sb[wave][h * K1 + 64 + lane]   = f2bf(acc[h][1]);
            sb[wave][h * K1 + 128 + lane]  = f2bf(acc[h][2]);
            if (lane < 32) {
                unsigned short v3 = (lane < 8) ? f2bf(acc[h][3]) : (unsigned short)0;
                sb[wave][h * K1 + 192 + lane] = v3;
            }
        }
    } else {
        for (int j = lane; j < HSL; j += 64) sb[wave][j] = 0;
    }
    __syncthreads();
    const uint4* s4 = (const uint4*)(&sb[0][0]);
    uint4* d4 = (uint4*)(xaggb + (size_t)blockIdx.x * 8 * HSL);
    for (int c = threadIdx.x; c < 8 * HSL / 8; c += 512) d4[c] = s4[c];
}

// ---------- fused GEMM: one head per block, 32-row tile, xh in LDS, PLAIN stores ----------
// grid (M_PAD/32 = 314, NH1 = 8); block 256 = 4 waves; one barrier.
__global__ __launch_bounds__(256) void fused_gemm(const unsigned short* __restrict__ xaggb,
                                                  const unsigned short* __restrict__ W1bt,
                                                  const float* __restrict__ b1,
                                                  const unsigned short* __restrict__ W2bt,
                                                  float* __restrict__ h2p) {
    __shared__ unsigned short xhf[32 * XHS];   // 27.1 KB
    const int wave = threadIdx.x >> 6;
    const int lane = threadIdx.x & 63;
    const int row  = lane & 15;
    const int kg   = lane >> 4;
    const int h    = blockIdx.y;
    const int m0   = blockIdx.x * 32;
    const int r0   = (wave & 1) * 16;
    const int c0   = (wave >> 1) * 208;
    const int c2   = (wave >> 1) * 112;

    // ---- gemm1: acc[j] = xagg_h[16 rows] @ W1_h[208 cols], K=224 ----
    const unsigned short* ap = xaggb + (size_t)(m0 + r0 + row) * HSL + h * K1 + kg * 8;
    const unsigned short* bp = W1bt + ((size_t)h * C1P + c0 + row) * K1 + kg * 8;
    f32x4 acc[13];
#pragma unroll
    for (int j = 0; j < 13; ++j) acc[j] = (f32x4){0.f, 0.f, 0.f, 0.f};
#pragma unroll
    for (int ks = 0; ks < 7; ++ks) {
        short8_t a = *(const short8_t*)(ap + ks * 32);
#pragma unroll
        for (int j = 0; j < 13; ++j) {
            short8_t b = *(const short8_t*)(bp + (size_t)j * 16 * K1 + ks * 32);
            acc[j] = __builtin_amdgcn_mfma_f32_16x16x32_bf16(a, b, acc[j], 0, 0, 0);
        }
    }

    // ---- bias + ELU -> LDS ----
#pragma unroll
    for (int j = 0; j < 13; ++j) {
        int cc = c0 + j * 16 + row;
        float bias = (cc < HID) ? b1[h * HID + cc] : 0.f;
#pragma unroll
        for (int r = 0; r < 4; ++r) {
            int rl = r0 + kg * 4 + r;
            float v = acc[j][r] + bias;
            v = v > 0.f ? v : (__expf(v) - 1.f);
            xhf[rl * XHS + cc] = f2bf(v);
        }
    }
    __syncthreads();

    // ---- gemm2: oacc[j] = xh[16 rows x 416] @ W2_h[112 cols] ----
    const unsigned short* bp2 = W2bt + (size_t)(c2 + row) * KALL + h * XH_K + kg * 8;
    const int rl = r0 + row;
    f32x4 oacc[7];
#pragma unroll
    for (int j = 0; j < 7; ++j) oacc[j] = (f32x4){0.f, 0.f, 0.f, 0.f};
#pragma unroll
    for (int ks = 0; ks < 13; ++ks) {
        short8_t a = *(const short8_t*)&xhf[rl * XHS + kg * 8 + ks * 32];
#pragma unroll
        for (int j = 0; j < 7; ++j) {
            short8_t b = *(const short8_t*)(bp2 + (size_t)j * 16 * KALL + ks * 32);
            oacc[j] = __builtin_amdgcn_mfma_f32_16x16x32_bf16(a, b, oacc[j], 0, 0, 0);
        }
    }

    // ---- plain stores to per-head partial buffer ----
    float* op = h2p + ((size_t)h * M_PAD + (m0 + r0 + kg * 4)) * OUT_FEAT;
#pragma unroll
    for (int j = 0; j < 7; ++j) {
        int cc = c2 + j * 16 + row;
        if (cc < OUT_FEAT) {
#pragma unroll
            for (int r = 0; r < 4; ++r)
                op[(size_t)r * OUT_FEAT + cc] = oacc[j][r];
        }
    }
}

// ---------- reduce 8 head-partials -> h2, fused layer-2 logits ----------
// grid M_PAD/4, block 256 = 4 waves, one row per wave
__global__ __launch_bounds__(256) void reduce_att2(const float* __restrict__ h2p,
                                                   const float* __restrict__ a_src,
                                                   const float* __restrict__ a_dst,
                                                   float* __restrict__ h2,
                                                   float* __restrict__ als,
                                                   float* __restrict__ ald) {
    const int wave = threadIdx.x >> 6;
    const int lane = threadIdx.x & 63;
    const int row  = blockIdx.x * 4 + wave;

    f32x4 sum = {0.f, 0.f, 0.f, 0.f};
    if (lane < 50) {
        const float* p = h2p + (size_t)row * OUT_FEAT + lane * 4;
#pragma unroll
        for (int h = 0; h < NH1; ++h)
            sum += *(const f32x4*)(p + (size_t)h * M_PAD * OUT_FEAT);
        *(f32x4*)(h2 + (size_t)row * OUT_FEAT + lane * 4) = sum;
    }
    float ss = 0.f, sd = 0.f;
    if (lane < 50) {
        f32x4 as = *(const f32x4*)(a_src + lane * 4);
        f32x4 ad = *(const f32x4*)(a_dst + lane * 4);
#pragma unroll
        for (int j = 0; j < 4; ++j) { ss += sum[j] * as[j]; sd += sum[j] * ad[j]; }
    }
    for (int off = 32; off; off >>= 1) {
        ss += __shfl_down(ss, off);
        sd += __shfl_down(sd, off);
    }
    if (lane == 0 && row < N_NODES) { als[row] = ss; ald[row] = sd; }
}

// ---------- layer-2 aggregation with online softmax ----------
__global__ __launch_bounds__(256) void agg2_csr(const float* __restrict__ h2,
                                                const float* __restrict__ als2,
                                                const float* __restrict__ ald2,
                                                const int* __restrict__ offs,
                                                const int* __restrict__ esrc,
                                                const float* __restrict__ b2,
                                                float* __restrict__ out) {
    const int n = blockIdx.x;
    const int k = threadIdx.x;
    const float aldn = ald2[n];
    const int beg = offs[n], end = offs[n + 1];

    // pass 1: online max + denominator (redundant across threads; broadcast loads)
    float m = -INFINITY, l = 0.f;
    for (int t = beg; t < end; ++t) {
        int s = esrc[t];
        float v = als2[s] + aldn;
        v = v > 0.f ? v : NEG_SLOPE * v;
        float mn = fmaxf(m, v);
        l = l * __expf(m - mn) + __expf(v - mn);
        m = mn;
    }
    const float inv_l = 1.f / l;

    if (k >= OUT_FEAT) return;
    // pass 2: weighted gather
    float acc = 0.f;
    for (int t = beg; t < end; ++t) {
        int s = esrc[t];
        float v = als2[s] + aldn;
        v = v > 0.f ? v : NEG_SLOPE * v;
        float a = __expf(v - m) * inv_l;
        acc += a * h2[(size_t)s * OUT_FEAT + k];
    }
    out[(size_t)n * OUT_FEAT + k] = acc + b2[k];
}

// ---------- launch ----------
extern "C" void kernel_launch(void* const* d_in, const int* in_sizes, int n_in,
                              void* d_out, int out_size, void* d_ws, size_t ws_size,
                              hipStream_t stream) {
    const float* X   = (const float*)d_in[0];
    const int*   ei  = (const int*)d_in[1];
    const float* W1  = (const float*)d_in[2];
    const float* as1 = (const float*)d_in[3];
    const float* ad1 = (const float*)d_in[4];
    const float* b1  = (const float*)d_in[5];
    const float* W2  = (const float*)d_in[6];
    const float* as2 = (const float*)d_in[7];
    const float* ad2 = (const float*)d_in[8];
    const float* b2  = (const float*)d_in[9];
    float* out = (float*)d_out;

    char* base = (char*)d_ws;
    auto carve = [&](size_t bytes) -> void* {
        void* p = (void*)base;
        base += (bytes + 255) & ~(size_t)255;
        return p;
    };
    float* p_src1 = (float*)carve(NH1 * IN_FEAT * 4);
    float* p_dst1 = (float*)carve(NH1 * IN_FEAT * 4);
    float* als1   = (float*)carve(N_NODES * NH1 * 4);
    float* ald1   = (float*)carve(N_NODES * NH1 * 4);
    float* als2   = (float*)carve(N_NODES * 4);
    float* ald2   = (float*)carve(N_NODES * 4);
    float* h2     = (float*)carve((size_t)M_PAD * OUT_FEAT * 4);                  // 8.0 MB
    int* counts   = (int*)carve(N_NODES * 4);
    int* cursor   = (int*)carve(N_NODES * 4);
    int* offs     = (int*)carve((N_NODES + 1) * 4);
    int* esrc     = (int*)carve(ET * 4);
    unsigned short* xaggb = (unsigned short*)carve((size_t)M_PAD * HSL * 2);      // 36 MB
    unsigned short* W1bt  = (unsigned short*)carve((size_t)NH1 * C1P * K1 * 2);   // 1.5 MB
    unsigned short* W2bt  = (unsigned short*)carve((size_t)N2P2 * KALL * 2);      // 1.7 MB
    float* h2p    = (float*)carve((size_t)NH1 * M_PAD * OUT_FEAT * 4);            // 64.3 MB

    // per-call init: only CSR counters (harness does not re-poison between replays)
    hipMemsetAsync(counts, 0, 2 * 40192, stream);  // counts + cursor (carve-aligned)

    // CSR + weight prep + layer-1 logits
    count_k<<<(ET + 255) / 256, 256, 0, stream>>>(ei, counts);
    scan_k<<<1, 1024, 0, stream>>>(counts, offs);
    scatter_k<<<(ET + 255) / 256, 256, 0, stream>>>(ei, offs, cursor, esrc);
    prep_w<<<(W1N + W2N + 255) / 256, 256, 0, stream>>>(W1, W2, W1bt, W2bt);
    pvec_k<<<(2 * NH1 * IN_FEAT + 255) / 256, 256, 0, stream>>>(W1, as1, ad1, p_src1, p_dst1);
    att1x<<<N_NODES, 512, 0, stream>>>(X, p_src1, p_dst1, als1, ald1);

    // Stage A: aggregated features (online softmax inside)
    agg1x<<<M_PAD / 8, 512, 0, stream>>>(X, als1, ald1, offs, esrc, xaggb);

    // fused GEMM1 (+bias+ELU) + GEMM2; plain stores to per-head partials
    fused_gemm<<<dim3(M_PAD / 32, NH1), 256, 0, stream>>>(xaggb, W1bt, b1, W2bt, h2p);

    // reduce partials -> h2, fused layer-2 logits
    reduce_att2<<<M_PAD / 4, 256, 0, stream>>>(h2p, as2, ad2, h2, als2, ald2);

    // layer-2 aggregation (online softmax inside)
    agg2_csr<<<N_NODES, 256, 0, stream>>>(h2, als2, ald2, offs, esrc, b2, out);
}

// Round 8
// 337.714 us; speedup vs baseline: 1.5167x; 1.0049x over previous
//
#include <hip/hip_runtime.h>
#include <math.h>

#define N_NODES 10000
#define N_EDGES 80000
#define ET (N_EDGES + N_NODES)   // 90000 edges incl. self-loops
#define IN_FEAT 200
#define HID 400
#define NH1 8
#define F1 (NH1 * HID)           // 3200
#define OUT_FEAT 200
#define NEG_SLOPE 0.2f

#define M_PAD 10048              // 157 * 64
#define K1 224                   // per-head K pad (200 -> 224 = 7*32)
#define HSL (NH1 * K1)           // 1792 bf16 per node in xagg
#define XH_K 416                 // per-head hidden K pad (400 -> 416 = 13*32)
#define C1P 416                  // W1bt col pad (400 -> 416)
#define KALL (NH1 * XH_K)        // 3328 = gemm2 B row length
#define N2P2 256                 // W2bt row pad (cols of h2)
#define XHS 424                  // LDS xh row stride (ushorts)

typedef __attribute__((ext_vector_type(8))) short short8_t;
typedef __attribute__((ext_vector_type(4))) float f32x4;

// ---------- helpers ----------

__device__ inline void edge_sd(const int* __restrict__ ei, int e, int& s, int& d) {
    if (e < N_EDGES) { s = ei[e]; d = ei[N_EDGES + e]; }
    else { s = e - N_EDGES; d = s; }
}

__device__ inline unsigned short f2bf(float x) {
    unsigned u = __float_as_uint(x);
    unsigned r = u + 0x7FFFu + ((u >> 16) & 1u);
    return (unsigned short)(r >> 16);
}

// ---------- weight prep (merged): W1bt[h][c<416][k<224], W2bt[c<256][h*416+k1] ----------
#define W1N (NH1 * C1P * K1)     // 745472
#define W2N (N2P2 * KALL)        // 851968
__global__ __launch_bounds__(256) void prep_w(const float* __restrict__ W1,
                                              const float* __restrict__ W2,
                                              unsigned short* __restrict__ W1bt,
                                              unsigned short* __restrict__ W2bt) {
    int idx = blockIdx.x * blockDim.x + threadIdx.x;
    if (idx < W1N) {
        int h = idx / (C1P * K1);
        int rem = idx - h * (C1P * K1);
        int c = rem / K1, k = rem - c * K1;
        float v = (k < IN_FEAT && c < HID) ? W1[(size_t)k * F1 + h * HID + c] : 0.f;
        W1bt[idx] = f2bf(v);
    } else if (idx < W1N + W2N) {
        int i2 = idx - W1N;
        int c = i2 / KALL;
        int rem = i2 - c * KALL;
        int h = rem / XH_K, k1 = rem - h * XH_K;
        float v = (c < OUT_FEAT && k1 < HID) ? W2[(size_t)(h * HID + k1) * OUT_FEAT + c] : 0.f;
        W2bt[i2] = f2bf(v);
    }
}

// ---------- p-vectors ----------
__global__ __launch_bounds__(256) void pvec_k(const float* __restrict__ W1,
                                              const float* __restrict__ a_src,
                                              const float* __restrict__ a_dst,
                                              float* __restrict__ p_src,
                                              float* __restrict__ p_dst) {
    int idx = blockIdx.x * blockDim.x + threadIdx.x;
    if (idx >= 2 * NH1 * IN_FEAT) return;
    int which = idx / (NH1 * IN_FEAT);
    int r = idx - which * (NH1 * IN_FEAT);
    int h = r / IN_FEAT, k = r - h * IN_FEAT;
    const float* av = (which == 0 ? a_src : a_dst) + h * HID;
    const float* wrow = W1 + (size_t)k * F1 + h * HID;
    float acc = 0.f;
    for (int c = 0; c < HID; ++c) acc += wrow[c] * av[c];
    (which == 0 ? p_src : p_dst)[h * IN_FEAT + k] = acc;
}

// ---------- attention logits layer 1 ----------
__global__ __launch_bounds__(512) void att1x(const float* __restrict__ X,
                                             const float* __restrict__ p_src,
                                             const float* __restrict__ p_dst,
                                             float* __restrict__ als,
                                             float* __restrict__ ald) {
    const int n    = blockIdx.x;
    const int head = threadIdx.x >> 6;
    const int lane = threadIdx.x & 63;
    const float* xp = X + (size_t)n * IN_FEAT;
    const float* ps = p_src + head * IN_FEAT;
    const float* pd = p_dst + head * IN_FEAT;
    float ss = 0.f, sd = 0.f;
    for (int k = lane; k < IN_FEAT; k += 64) {
        float v = xp[k];
        ss += v * ps[k];
        sd += v * pd[k];
    }
    for (int off = 32; off; off >>= 1) {
        ss += __shfl_down(ss, off);
        sd += __shfl_down(sd, off);
    }
    if (lane == 0) { als[n * NH1 + head] = ss; ald[n * NH1 + head] = sd; }
}

// ---------- CSR build ----------
__global__ __launch_bounds__(256) void count_k(const int* __restrict__ ei, int* __restrict__ counts) {
    int e = blockIdx.x * blockDim.x + threadIdx.x;
    if (e >= ET) return;
    int s, d; edge_sd(ei, e, s, d);
    atomicAdd(&counts[d], 1);
}

__global__ __launch_bounds__(1024) void scan_k(const int* __restrict__ counts, int* __restrict__ offs) {
    __shared__ int part[1024];
    const int tid = threadIdx.x;
    const int base = tid * 10;
    int loc[10];
    int s = 0;
    for (int i = 0; i < 10; ++i) {
        int idx = base + i;
        int c = (idx < N_NODES) ? counts[idx] : 0;
        loc[i] = s; s += c;
    }
    part[tid] = s;
    __syncthreads();
    for (int off = 1; off < 1024; off <<= 1) {
        int v = (tid >= off) ? part[tid - off] : 0;
        __syncthreads();
        part[tid] += v;
        __syncthreads();
    }
    int pre = (tid > 0) ? part[tid - 1] : 0;
    for (int i = 0; i < 10; ++i) {
        int idx = base + i;
        if (idx < N_NODES) offs[idx] = pre + loc[i];
    }
    if (tid == 1023) offs[N_NODES] = part[1023];
}

__global__ __launch_bounds__(256) void scatter_k(const int* __restrict__ ei,
                                                 const int* __restrict__ offs,
                                                 int* __restrict__ cursor,
                                                 int* __restrict__ esrc) {
    int e = blockIdx.x * blockDim.x + threadIdx.x;
    if (e >= ET) return;
    int s, d; edge_sd(ei, e, s, d);
    int pos = atomicAdd(&cursor[d], 1);
    esrc[offs[d] + pos] = s;
}

// ---------- Stage A: online softmax + aggregation: xagg[n,h,0:224] (bf16) ----------
__global__ __launch_bounds__(512) void agg1x(const float* __restrict__ X,
                                             const float* __restrict__ als1,
                                             const float* __restrict__ ald1,
                                             const int* __restrict__ offs,
                                             const int* __restrict__ esrc,
                                             unsigned short* __restrict__ xaggb) {
    __shared__ unsigned short sb[8][HSL];   // 28672 B
    const int wave = threadIdx.x >> 6;
    const int lane = threadIdx.x & 63;
    const int n = blockIdx.x * 8 + wave;

    if (n < N_NODES) {
        float acc[NH1][4];
#pragma unroll
        for (int h = 0; h < NH1; ++h)
#pragma unroll
            for (int g = 0; g < 4; ++g) acc[h][g] = 0.f;

        const int beg = offs[n], end = offs[n + 1];
        float aldv = 0.f, m = -INFINITY, l = 0.f;
        if (lane < NH1) aldv = ald1[n * NH1 + lane];

        // pass 1: online max + denominator (lanes 0..7 = heads)
        for (int t = beg; t < end; ++t) {
            const int s = esrc[t];
            if (lane < NH1) {
                float v = als1[s * NH1 + lane] + aldv;
                v = v > 0.f ? v : NEG_SLOPE * v;
                float mn = fmaxf(m, v);
                l = l * __expf(m - mn) + __expf(v - mn);
                m = mn;
            }
        }
        const float inv_l = (lane < NH1) ? 1.f / l : 0.f;

        // pass 2: weighted aggregation
        for (int t = beg; t < end; ++t) {
            const int s = esrc[t];
            float aval = 0.f;
            if (lane < NH1) {
                float v = als1[s * NH1 + lane] + aldv;
                v = v > 0.f ? v : NEG_SLOPE * v;
                aval = __expf(v - m) * inv_l;
            }
            const float* xp = X + (size_t)s * IN_FEAT;
            float x0 = xp[lane];
            float x1 = xp[64 + lane];
            float x2 = xp[128 + lane];
            float x3 = (lane < 8) ? xp[192 + lane] : 0.f;
#pragma unroll
            for (int h = 0; h < NH1; ++h) {
                float a = __shfl(aval, h);
                acc[h][0] += a * x0;
                acc[h][1] += a * x1;
                acc[h][2] += a * x2;
                acc[h][3] += a * x3;
            }
        }
#pragma unroll
        for (int h = 0; h < NH1; ++h) {
            sb[wave][h * K1 + lane]        = f2bf(acc[h][0]);
            sb[wave][h * K1 + 64 + lane]   = f2bf(acc[h][1]);
            sb[wave][h * K1 + 128 + lane]  = f2bf(acc[h][2]);
            if (lane < 32) {
                unsigned short v3 = (lane < 8) ? f2bf(acc[h][3]) : (unsigned short)0;
                sb[wave][h * K1 + 192 + lane] = v3;
            }
        }
    } else {
        for (int j = lane; j < HSL; j += 64) sb[wave][j] = 0;
    }
    __syncthreads();
    const uint4* s4 = (const uint4*)(&sb[0][0]);
    uint4* d4 = (uint4*)(xaggb + (size_t)blockIdx.x * 8 * HSL);
    for (int c = threadIdx.x; c < 8 * HSL / 8; c += 512) d4[c] = s4[c];
}

// ---------- fused GEMM v3: 64-row tile, 1 head, 8 waves, register-pipelined B ----------
// grid (M_PAD/64 = 157, NH1 = 8); block 512.
// wave w: rows r0=(w&3)*16; gemm1 cols c0=(w>>2)*208 (13 frags); gemm2 cols c2=(w>>2)*112 (7 frags)
__global__ __launch_bounds__(512) void fused_gemm(const unsigned short* __restrict__ xaggb,
                                                  const unsigned short* __restrict__ W1bt,
                                                  const float* __restrict__ b1,
                                                  const unsigned short* __restrict__ W2bt,
                                                  float* __restrict__ h2p) {
    __shared__ unsigned short xhf[64 * XHS];   // 54.3 KB
    const int wave = threadIdx.x >> 6;
    const int lane = threadIdx.x & 63;
    const int row  = lane & 15;
    const int kg   = lane >> 4;
    const int h    = blockIdx.y;
    const int m0   = blockIdx.x * 64;
    const int r0   = (wave & 3) * 16;
    const int c0   = (wave >> 2) * 208;
    const int c2   = (wave >> 2) * 112;

    // ---- gemm1: acc[j] = xagg_h[16 rows] @ W1_h[208 cols], K=224, B double-buffered ----
    const unsigned short* ap = xaggb + (size_t)(m0 + r0 + row) * HSL + h * K1 + kg * 8;
    const unsigned short* bp = W1bt + ((size_t)h * C1P + c0 + row) * K1 + kg * 8;

    f32x4 acc[13];
    short8_t breg[2][13];
    short8_t areg[2];
#pragma unroll
    for (int j = 0; j < 13; ++j) acc[j] = (f32x4){0.f, 0.f, 0.f, 0.f};
    areg[0] = *(const short8_t*)(ap);
#pragma unroll
    for (int j = 0; j < 13; ++j) breg[0][j] = *(const short8_t*)(bp + (size_t)j * 16 * K1);
#pragma unroll
    for (int ks = 0; ks < 7; ++ks) {
        const int cur = ks & 1, nxt = cur ^ 1;
        if (ks < 6) {
            areg[nxt] = *(const short8_t*)(ap + (ks + 1) * 32);
#pragma unroll
            for (int j = 0; j < 13; ++j)
                breg[nxt][j] = *(const short8_t*)(bp + (size_t)j * 16 * K1 + (ks + 1) * 32);
        }
#pragma unroll
        for (int j = 0; j < 13; ++j)
            acc[j] = __builtin_amdgcn_mfma_f32_16x16x32_bf16(areg[cur], breg[cur][j], acc[j], 0, 0, 0);
    }

    // ---- bias + ELU -> LDS ----
#pragma unroll
    for (int j = 0; j < 13; ++j) {
        int cc = c0 + j * 16 + row;
        float bias = (cc < HID) ? b1[h * HID + cc] : 0.f;
#pragma unroll
        for (int r = 0; r < 4; ++r) {
            int rl = r0 + kg * 4 + r;
            float v = acc[j][r] + bias;
            v = v > 0.f ? v : (__expf(v) - 1.f);
            xhf[rl * XHS + cc] = f2bf(v);
        }
    }

    // ---- preload gemm2 B ks=0 (in flight across the barrier) ----
    const unsigned short* bp2 = W2bt + (size_t)(c2 + row) * KALL + h * XH_K + kg * 8;
    short8_t breg2[2][7];
#pragma unroll
    for (int j = 0; j < 7; ++j) breg2[0][j] = *(const short8_t*)(bp2 + (size_t)j * 16 * KALL);

    __syncthreads();

    // ---- gemm2: oacc[j] = xh[16 rows x 416] @ W2_h[112 cols], A from LDS, B pipelined ----
    const int rl = r0 + row;
    f32x4 oacc[7];
#pragma unroll
    for (int j = 0; j < 7; ++j) oacc[j] = (f32x4){0.f, 0.f, 0.f, 0.f};
#pragma unroll
    for (int ks = 0; ks < 13; ++ks) {
        const int cur = ks & 1, nxt = cur ^ 1;
        if (ks < 12) {
#pragma unroll
            for (int j = 0; j < 7; ++j)
                breg2[nxt][j] = *(const short8_t*)(bp2 + (size_t)j * 16 * KALL + (ks + 1) * 32);
        }
        short8_t a = *(const short8_t*)&xhf[rl * XHS + kg * 8 + ks * 32];
#pragma unroll
        for (int j = 0; j < 7; ++j)
            oacc[j] = __builtin_amdgcn_mfma_f32_16x16x32_bf16(a, breg2[cur][j], oacc[j], 0, 0, 0);
    }

    // ---- plain stores to per-head partial buffer ----
    float* op = h2p + ((size_t)h * M_PAD + (m0 + r0 + kg * 4)) * OUT_FEAT;
#pragma unroll
    for (int j = 0; j < 7; ++j) {
        int cc = c2 + j * 16 + row;
        if (cc < OUT_FEAT) {
#pragma unroll
            for (int r = 0; r < 4; ++r)
                op[(size_t)r * OUT_FEAT + cc] = oacc[j][r];
        }
    }
}

// ---------- reduce 8 head-partials -> h2, fused layer-2 logits ----------
// grid M_PAD/4, block 256 = 4 waves, one row per wave
__global__ __launch_bounds__(256) void reduce_att2(const float* __restrict__ h2p,
                                                   const float* __restrict__ a_src,
                                                   const float* __restrict__ a_dst,
                                                   float* __restrict__ h2,
                                                   float* __restrict__ als,
                                                   float* __restrict__ ald) {
    const int wave = threadIdx.x >> 6;
    const int lane = threadIdx.x & 63;
    const int row  = blockIdx.x * 4 + wave;

    f32x4 sum = {0.f, 0.f, 0.f, 0.f};
    if (lane < 50) {
        const float* p = h2p + (size_t)row * OUT_FEAT + lane * 4;
#pragma unroll
        for (int h = 0; h < NH1; ++h)
            sum += *(const f32x4*)(p + (size_t)h * M_PAD * OUT_FEAT);
        *(f32x4*)(h2 + (size_t)row * OUT_FEAT + lane * 4) = sum;
    }
    float ss = 0.f, sd = 0.f;
    if (lane < 50) {
        f32x4 as = *(const f32x4*)(a_src + lane * 4);
        f32x4 ad = *(const f32x4*)(a_dst + lane * 4);
#pragma unroll
        for (int j = 0; j < 4; ++j) { ss += sum[j] * as[j]; sd += sum[j] * ad[j]; }
    }
    for (int off = 32; off; off >>= 1) {
        ss += __shfl_down(ss, off);
        sd += __shfl_down(sd, off);
    }
    if (lane == 0 && row < N_NODES) { als[row] = ss; ald[row] = sd; }
}

// ---------- layer-2 aggregation with online softmax ----------
__global__ __launch_bounds__(256) void agg2_csr(const float* __restrict__ h2,
                                                const float* __restrict__ als2,
                                                const float* __restrict__ ald2,
                                                const int* __restrict__ offs,
                                                const int* __restrict__ esrc,
                                                const float* __restrict__ b2,
                                                float* __restrict__ out) {
    const int n = blockIdx.x;
    const int k = threadIdx.x;
    const float aldn = ald2[n];
    const int beg = offs[n], end = offs[n + 1];

    // pass 1: online max + denominator (redundant across threads; broadcast loads)
    float m = -INFINITY, l = 0.f;
    for (int t = beg; t < end; ++t) {
        int s = esrc[t];
        float v = als2[s] + aldn;
        v = v > 0.f ? v : NEG_SLOPE * v;
        float mn = fmaxf(m, v);
        l = l * __expf(m - mn) + __expf(v - mn);
        m = mn;
    }
    const float inv_l = 1.f / l;

    if (k >= OUT_FEAT) return;
    // pass 2: weighted gather
    float acc = 0.f;
    for (int t = beg; t < end; ++t) {
        int s = esrc[t];
        float v = als2[s] + aldn;
        v = v > 0.f ? v : NEG_SLOPE * v;
        float a = __expf(v - m) * inv_l;
        acc += a * h2[(size_t)s * OUT_FEAT + k];
    }
    out[(size_t)n * OUT_FEAT + k] = acc + b2[k];
}

// ---------- launch ----------
extern "C" void kernel_launch(void* const* d_in, const int* in_sizes, int n_in,
                              void* d_out, int out_size, void* d_ws, size_t ws_size,
                              hipStream_t stream) {
    const float* X   = (const float*)d_in[0];
    const int*   ei  = (const int*)d_in[1];
    const float* W1  = (const float*)d_in[2];
    const float* as1 = (const float*)d_in[3];
    const float* ad1 = (const float*)d_in[4];
    const float* b1  = (const float*)d_in[5];
    const float* W2  = (const float*)d_in[6];
    const float* as2 = (const float*)d_in[7];
    const float* ad2 = (const float*)d_in[8];
    const float* b2  = (const float*)d_in[9];
    float* out = (float*)d_out;

    char* base = (char*)d_ws;
    auto carve = [&](size_t bytes) -> void* {
        void* p = (void*)base;
        base += (bytes + 255) & ~(size_t)255;
        return p;
    };
    float* p_src1 = (float*)carve(NH1 * IN_FEAT * 4);
    float* p_dst1 = (float*)carve(NH1 * IN_FEAT * 4);
    float* als1   = (float*)carve(N_NODES * NH1 * 4);
    float* ald1   = (float*)carve(N_NODES * NH1 * 4);
    float* als2   = (float*)carve(N_NODES * 4);
    float* ald2   = (float*)carve(N_NODES * 4);
    float* h2     = (float*)carve((size_t)M_PAD * OUT_FEAT * 4);                  // 8.0 MB
    int* counts   = (int*)carve(N_NODES * 4);
    int* cursor   = (int*)carve(N_NODES * 4);
    int* offs     = (int*)carve((N_NODES + 1) * 4);
    int* esrc     = (int*)carve(ET * 4);
    unsigned short* xaggb = (unsigned short*)carve((size_t)M_PAD * HSL * 2);      // 36 MB
    unsigned short* W1bt  = (unsigned short*)carve((size_t)NH1 * C1P * K1 * 2);   // 1.5 MB
    unsigned short* W2bt  = (unsigned short*)carve((size_t)N2P2 * KALL * 2);      // 1.7 MB
    float* h2p    = (float*)carve((size_t)NH1 * M_PAD * OUT_FEAT * 4);            // 64.3 MB

    // per-call init: only CSR counters (harness does not re-poison between replays)
    hipMemsetAsync(counts, 0, 2 * 40192, stream);  // counts + cursor (carve-aligned)

    // CSR + weight prep + layer-1 logits
    count_k<<<(ET + 255) / 256, 256, 0, stream>>>(ei, counts);
    scan_k<<<1, 1024, 0, stream>>>(counts, offs);
    scatter_k<<<(ET + 255) / 256, 256, 0, stream>>>(ei, offs, cursor, esrc);
    prep_w<<<(W1N + W2N + 255) / 256, 256, 0, stream>>>(W1, W2, W1bt, W2bt);
    pvec_k<<<(2 * NH1 * IN_FEAT + 255) / 256, 256, 0, stream>>>(W1, as1, ad1, p_src1, p_dst1);
    att1x<<<N_NODES, 512, 0, stream>>>(X, p_src1, p_dst1, als1, ald1);

    // Stage A: aggregated features (online softmax inside)
    agg1x<<<M_PAD / 8, 512, 0, stream>>>(X, als1, ald1, offs, esrc, xaggb);

    // fused GEMM1 (+bias+ELU) + GEMM2; register-pipelined B, plain stores
    fused_gemm<<<dim3(M_PAD / 64, NH1), 512, 0, stream>>>(xaggb, W1bt, b1, W2bt, h2p);

    // reduce partials -> h2, fused layer-2 logits
    reduce_att2<<<M_PAD / 4, 256, 0, stream>>>(h2p, as2, ad2, h2, als2, ald2);

    // layer-2 aggregation (online softmax inside)
    agg2_csr<<<N_NODES, 256, 0, stream>>>(h2, als2, ald2, offs, esrc, b2, out);
}

// Round 9
// 309.880 us; speedup vs baseline: 1.6530x; 1.0898x over previous
//
#include <hip/hip_runtime.h>
#include <math.h>

#define N_NODES 10000
#define N_EDGES 80000
#define ET (N_EDGES + N_NODES)   // 90000 edges incl. self-loops
#define IN_FEAT 200
#define HID 400
#define NH1 8
#define F1 (NH1 * HID)           // 3200
#define OUT_FEAT 200
#define NEG_SLOPE 0.2f

#define M_PAD 10048              // 157 * 64
#define K1 224                   // per-head K pad (200 -> 224 = 7*32)
#define HSL (NH1 * K1)           // 1792 bf16 per node in xagg
#define XH_K 416                 // per-head hidden K pad (400 -> 416 = 13*32)
#define C1P 416                  // W1bt col pad (400 -> 416)
#define KALL (NH1 * XH_K)        // 3328 = gemm2 B row length
#define N2P2 256                 // W2bt row pad (cols of h2)
#define XHS 424                  // LDS xh row stride (ushorts)

typedef __attribute__((ext_vector_type(8))) short short8_t;
typedef __attribute__((ext_vector_type(4))) float f32x4;

// ---------- helpers ----------

__device__ inline void edge_sd(const int* __restrict__ ei, int e, int& s, int& d) {
    if (e < N_EDGES) { s = ei[e]; d = ei[N_EDGES + e]; }
    else { s = e - N_EDGES; d = s; }
}

__device__ inline unsigned short f2bf(float x) {
    unsigned u = __float_as_uint(x);
    unsigned r = u + 0x7FFFu + ((u >> 16) & 1u);
    return (unsigned short)(r >> 16);
}

// ---------- weight prep (merged): W1bt[h][c<416][k<224], W2bt[c<256][h*416+k1] ----------
#define W1N (NH1 * C1P * K1)     // 745472
#define W2N (N2P2 * KALL)        // 851968
__global__ __launch_bounds__(256) void prep_w(const float* __restrict__ W1,
                                              const float* __restrict__ W2,
                                              unsigned short* __restrict__ W1bt,
                                              unsigned short* __restrict__ W2bt) {
    int idx = blockIdx.x * blockDim.x + threadIdx.x;
    if (idx < W1N) {
        int h = idx / (C1P * K1);
        int rem = idx - h * (C1P * K1);
        int c = rem / K1, k = rem - c * K1;
        float v = (k < IN_FEAT && c < HID) ? W1[(size_t)k * F1 + h * HID + c] : 0.f;
        W1bt[idx] = f2bf(v);
    } else if (idx < W1N + W2N) {
        int i2 = idx - W1N;
        int c = i2 / KALL;
        int rem = i2 - c * KALL;
        int h = rem / XH_K, k1 = rem - h * XH_K;
        float v = (c < OUT_FEAT && k1 < HID) ? W2[(size_t)(h * HID + k1) * OUT_FEAT + c] : 0.f;
        W2bt[i2] = f2bf(v);
    }
}

// ---------- p-vectors ----------
__global__ __launch_bounds__(256) void pvec_k(const float* __restrict__ W1,
                                              const float* __restrict__ a_src,
                                              const float* __restrict__ a_dst,
                                              float* __restrict__ p_src,
                                              float* __restrict__ p_dst) {
    int idx = blockIdx.x * blockDim.x + threadIdx.x;
    if (idx >= 2 * NH1 * IN_FEAT) return;
    int which = idx / (NH1 * IN_FEAT);
    int r = idx - which * (NH1 * IN_FEAT);
    int h = r / IN_FEAT, k = r - h * IN_FEAT;
    const float* av = (which == 0 ? a_src : a_dst) + h * HID;
    const float* wrow = W1 + (size_t)k * F1 + h * HID;
    float acc = 0.f;
    for (int c = 0; c < HID; ++c) acc += wrow[c] * av[c];
    (which == 0 ? p_src : p_dst)[h * IN_FEAT + k] = acc;
}

// ---------- attention logits layer 1 ----------
__global__ __launch_bounds__(512) void att1x(const float* __restrict__ X,
                                             const float* __restrict__ p_src,
                                             const float* __restrict__ p_dst,
                                             float* __restrict__ als,
                                             float* __restrict__ ald) {
    const int n    = blockIdx.x;
    const int head = threadIdx.x >> 6;
    const int lane = threadIdx.x & 63;
    const float* xp = X + (size_t)n * IN_FEAT;
    const float* ps = p_src + head * IN_FEAT;
    const float* pd = p_dst + head * IN_FEAT;
    float ss = 0.f, sd = 0.f;
    for (int k = lane; k < IN_FEAT; k += 64) {
        float v = xp[k];
        ss += v * ps[k];
        sd += v * pd[k];
    }
    for (int off = 32; off; off >>= 1) {
        ss += __shfl_down(ss, off);
        sd += __shfl_down(sd, off);
    }
    if (lane == 0) { als[n * NH1 + head] = ss; ald[n * NH1 + head] = sd; }
}

// ---------- CSR build ----------
__global__ __launch_bounds__(256) void count_k(const int* __restrict__ ei, int* __restrict__ counts) {
    int e = blockIdx.x * blockDim.x + threadIdx.x;
    if (e >= ET) return;
    int s, d; edge_sd(ei, e, s, d);
    atomicAdd(&counts[d], 1);
}

__global__ __launch_bounds__(1024) void scan_k(const int* __restrict__ counts, int* __restrict__ offs) {
    __shared__ int part[1024];
    const int tid = threadIdx.x;
    const int base = tid * 10;
    int loc[10];
    int s = 0;
    for (int i = 0; i < 10; ++i) {
        int idx = base + i;
        int c = (idx < N_NODES) ? counts[idx] : 0;
        loc[i] = s; s += c;
    }
    part[tid] = s;
    __syncthreads();
    for (int off = 1; off < 1024; off <<= 1) {
        int v = (tid >= off) ? part[tid - off] : 0;
        __syncthreads();
        part[tid] += v;
        __syncthreads();
    }
    int pre = (tid > 0) ? part[tid - 1] : 0;
    for (int i = 0; i < 10; ++i) {
        int idx = base + i;
        if (idx < N_NODES) offs[idx] = pre + loc[i];
    }
    if (tid == 1023) offs[N_NODES] = part[1023];
}

__global__ __launch_bounds__(256) void scatter_k(const int* __restrict__ ei,
                                                 const int* __restrict__ offs,
                                                 int* __restrict__ cursor,
                                                 int* __restrict__ esrc) {
    int e = blockIdx.x * blockDim.x + threadIdx.x;
    if (e >= ET) return;
    int s, d; edge_sd(ei, e, s, d);
    int pos = atomicAdd(&cursor[d], 1);
    esrc[offs[d] + pos] = s;
}

// ---------- Stage A: online softmax + aggregation: xagg[n,h,0:224] (bf16) ----------
__global__ __launch_bounds__(512) void agg1x(const float* __restrict__ X,
                                             const float* __restrict__ als1,
                                             const float* __restrict__ ald1,
                                             const int* __restrict__ offs,
                                             const int* __restrict__ esrc,
                                             unsigned short* __restrict__ xaggb) {
    __shared__ unsigned short sb[8][HSL];   // 28672 B
    const int wave = threadIdx.x >> 6;
    const int lane = threadIdx.x & 63;
    const int n = blockIdx.x * 8 + wave;

    if (n < N_NODES) {
        float acc[NH1][4];
#pragma unroll
        for (int h = 0; h < NH1; ++h)
#pragma unroll
            for (int g = 0; g < 4; ++g) acc[h][g] = 0.f;

        const int beg = offs[n], end = offs[n + 1];
        float aldv = 0.f, m = -INFINITY, l = 0.f;
        if (lane < NH1) aldv = ald1[n * NH1 + lane];

        // pass 1: online max + denominator (lanes 0..7 = heads)
        for (int t = beg; t < end; ++t) {
            const int s = esrc[t];
            if (lane < NH1) {
                float v = als1[s * NH1 + lane] + aldv;
                v = v > 0.f ? v : NEG_SLOPE * v;
                float mn = fmaxf(m, v);
                l = l * __expf(m - mn) + __expf(v - mn);
                m = mn;
            }
        }
        const float inv_l = (lane < NH1) ? 1.f / l : 0.f;

        // pass 2: weighted aggregation
        for (int t = beg; t < end; ++t) {
            const int s = esrc[t];
            float aval = 0.f;
            if (lane < NH1) {
                float v = als1[s * NH1 + lane] + aldv;
                v = v > 0.f ? v : NEG_SLOPE * v;
                aval = __expf(v - m) * inv_l;
            }
            const float* xp = X + (size_t)s * IN_FEAT;
            float x0 = xp[lane];
            float x1 = xp[64 + lane];
            float x2 = xp[128 + lane];
            float x3 = (lane < 8) ? xp[192 + lane] : 0.f;
#pragma unroll
            for (int h = 0; h < NH1; ++h) {
                float a = __shfl(aval, h);
                acc[h][0] += a * x0;
                acc[h][1] += a * x1;
                acc[h][2] += a * x2;
                acc[h][3] += a * x3;
            }
        }
#pragma unroll
        for (int h = 0; h < NH1; ++h) {
            sb[wave][h * K1 + lane]        = f2bf(acc[h][0]);
            sb[wave][h * K1 + 64 + lane]   = f2bf(acc[h][1]);
            sb[wave][h * K1 + 128 + lane]  = f2bf(acc[h][2]);
            if (lane < 32) {
                unsigned short v3 = (lane < 8) ? f2bf(acc[h][3]) : (unsigned short)0;
                sb[wave][h * K1 + 192 + lane] = v3;
            }
        }
    } else {
        for (int j = lane; j < HSL; j += 64) sb[wave][j] = 0;
    }
    __syncthreads();
    const uint4* s4 = (const uint4*)(&sb[0][0]);
    uint4* d4 = (uint4*)(xaggb + (size_t)blockIdx.x * 8 * HSL);
    for (int c = threadIdx.x; c < 8 * HSL / 8; c += 512) d4[c] = s4[c];
}

// ---------- fused GEMM v4: 64-row block, 4 waves, wave = 32 rows x 208/112 cols ----------
// grid (M_PAD/64 = 157, NH1 = 8); block 256; __launch_bounds__(256,2) -> VGPR cap 256.
// Wave w: rg = w&1 (rows r0=rg*32), cg = w>>1 (gemm1 cols cg*208, gemm2 cols cg*112).
// acc[2][13] = 104 VGPRs forces the allocator to keep the 13-load B batches in regs.
__global__ __launch_bounds__(256, 2) void fused_gemm(const unsigned short* __restrict__ xaggb,
                                                     const unsigned short* __restrict__ W1bt,
                                                     const float* __restrict__ b1,
                                                     const unsigned short* __restrict__ W2bt,
                                                     float* __restrict__ h2p) {
    __shared__ unsigned short xhf[64 * XHS];   // 54.3 KB
    const int wave = threadIdx.x >> 6;
    const int lane = threadIdx.x & 63;
    const int row  = lane & 15;
    const int kg   = lane >> 4;
    const int h    = blockIdx.y;
    const int m0   = blockIdx.x * 64;
    const int rg   = wave & 1;
    const int cg   = wave >> 1;
    const int r0   = rg * 32;
    const int c0   = cg * 208;
    const int c2   = cg * 112;

    // ---- gemm1: acc[mf][j] = xagg_h[32 rows] @ W1_h[208 cols], K=224 ----
    const unsigned short* ap = xaggb + (size_t)(m0 + r0 + row) * HSL + h * K1 + kg * 8;
    const unsigned short* bp = W1bt + ((size_t)h * C1P + c0 + row) * K1 + kg * 8;

    f32x4 acc[2][13];
#pragma unroll
    for (int mf = 0; mf < 2; ++mf)
#pragma unroll
        for (int j = 0; j < 13; ++j) acc[mf][j] = (f32x4){0.f, 0.f, 0.f, 0.f};

#pragma unroll
    for (int ks = 0; ks < 7; ++ks) {
        short8_t b[13];
#pragma unroll
        for (int j = 0; j < 13; ++j)
            b[j] = *(const short8_t*)(bp + (size_t)j * 16 * K1 + ks * 32);
        short8_t a0 = *(const short8_t*)(ap + ks * 32);
        short8_t a1 = *(const short8_t*)(ap + (size_t)16 * HSL + ks * 32);
#pragma unroll
        for (int j = 0; j < 13; ++j) {
            acc[0][j] = __builtin_amdgcn_mfma_f32_16x16x32_bf16(a0, b[j], acc[0][j], 0, 0, 0);
            acc[1][j] = __builtin_amdgcn_mfma_f32_16x16x32_bf16(a1, b[j], acc[1][j], 0, 0, 0);
        }
    }

    // ---- bias + ELU -> LDS ----
#pragma unroll
    for (int j = 0; j < 13; ++j) {
        int cc = c0 + j * 16 + row;
        float bias = (cc < HID) ? b1[h * HID + cc] : 0.f;
#pragma unroll
        for (int mf = 0; mf < 2; ++mf) {
#pragma unroll
            for (int r = 0; r < 4; ++r) {
                int rl = r0 + mf * 16 + kg * 4 + r;
                float v = acc[mf][j][r] + bias;
                v = v > 0.f ? v : (__expf(v) - 1.f);
                xhf[rl * XHS + cc] = f2bf(v);
            }
        }
    }
    __syncthreads();

    // ---- gemm2: oacc[mf][j] = xh[32 rows x 416] @ W2_h[112 cols], A from LDS ----
    const unsigned short* bp2 = W2bt + (size_t)(c2 + row) * KALL + h * XH_K + kg * 8;
    const int rl0 = r0 + row, rl1 = r0 + 16 + row;
    f32x4 oacc[2][7];
#pragma unroll
    for (int mf = 0; mf < 2; ++mf)
#pragma unroll
        for (int j = 0; j < 7; ++j) oacc[mf][j] = (f32x4){0.f, 0.f, 0.f, 0.f};

#pragma unroll
    for (int ks = 0; ks < 13; ++ks) {
        short8_t b[7];
#pragma unroll
        for (int j = 0; j < 7; ++j)
            b[j] = *(const short8_t*)(bp2 + (size_t)j * 16 * KALL + ks * 32);
        short8_t a0 = *(const short8_t*)&xhf[rl0 * XHS + kg * 8 + ks * 32];
        short8_t a1 = *(const short8_t*)&xhf[rl1 * XHS + kg * 8 + ks * 32];
#pragma unroll
        for (int j = 0; j < 7; ++j) {
            oacc[0][j] = __builtin_amdgcn_mfma_f32_16x16x32_bf16(a0, b[j], oacc[0][j], 0, 0, 0);
            oacc[1][j] = __builtin_amdgcn_mfma_f32_16x16x32_bf16(a1, b[j], oacc[1][j], 0, 0, 0);
        }
    }

    // ---- plain stores to per-head partial buffer ----
#pragma unroll
    for (int mf = 0; mf < 2; ++mf) {
        float* op = h2p + ((size_t)h * M_PAD + (m0 + r0 + mf * 16 + kg * 4)) * OUT_FEAT;
#pragma unroll
        for (int j = 0; j < 7; ++j) {
            int cc = c2 + j * 16 + row;
            if (cc < OUT_FEAT) {
#pragma unroll
                for (int r = 0; r < 4; ++r)
                    op[(size_t)r * OUT_FEAT + cc] = oacc[mf][j][r];
            }
        }
    }
}

// ---------- reduce 8 head-partials -> h2, fused layer-2 logits ----------
// grid M_PAD/4, block 256 = 4 waves, one row per wave
__global__ __launch_bounds__(256) void reduce_att2(const float* __restrict__ h2p,
                                                   const float* __restrict__ a_src,
                                                   const float* __restrict__ a_dst,
                                                   float* __restrict__ h2,
                                                   float* __restrict__ als,
                                                   float* __restrict__ ald) {
    const int wave = threadIdx.x >> 6;
    const int lane = threadIdx.x & 63;
    const int row  = blockIdx.x * 4 + wave;

    f32x4 sum = {0.f, 0.f, 0.f, 0.f};
    if (lane < 50) {
        const float* p = h2p + (size_t)row * OUT_FEAT + lane * 4;
#pragma unroll
        for (int h = 0; h < NH1; ++h)
            sum += *(const f32x4*)(p + (size_t)h * M_PAD * OUT_FEAT);
        *(f32x4*)(h2 + (size_t)row * OUT_FEAT + lane * 4) = sum;
    }
    float ss = 0.f, sd = 0.f;
    if (lane < 50) {
        f32x4 as = *(const f32x4*)(a_src + lane * 4);
        f32x4 ad = *(const f32x4*)(a_dst + lane * 4);
#pragma unroll
        for (int j = 0; j < 4; ++j) { ss += sum[j] * as[j]; sd += sum[j] * ad[j]; }
    }
    for (int off = 32; off; off >>= 1) {
        ss += __shfl_down(ss, off);
        sd += __shfl_down(sd, off);
    }
    if (lane == 0 && row < N_NODES) { als[row] = ss; ald[row] = sd; }
}

// ---------- layer-2 aggregation with online softmax ----------
__global__ __launch_bounds__(256) void agg2_csr(const float* __restrict__ h2,
                                                const float* __restrict__ als2,
                                                const float* __restrict__ ald2,
                                                const int* __restrict__ offs,
                                                const int* __restrict__ esrc,
                                                const float* __restrict__ b2,
                                                float* __restrict__ out) {
    const int n = blockIdx.x;
    const int k = threadIdx.x;
    const float aldn = ald2[n];
    const int beg = offs[n], end = offs[n + 1];

    // pass 1: online max + denominator (redundant across threads; broadcast loads)
    float m = -INFINITY, l = 0.f;
    for (int t = beg; t < end; ++t) {
        int s = esrc[t];
        float v = als2[s] + aldn;
        v = v > 0.f ? v : NEG_SLOPE * v;
        float mn = fmaxf(m, v);
        l = l * __expf(m - mn) + __expf(v - mn);
        m = mn;
    }
    const float inv_l = 1.f / l;

    if (k >= OUT_FEAT) return;
    // pass 2: weighted gather
    float acc = 0.f;
    for (int t = beg; t < end; ++t) {
        int s = esrc[t];
        float v = als2[s] + aldn;
        v = v > 0.f ? v : NEG_SLOPE * v;
        float a = __expf(v - m) * inv_l;
        acc += a * h2[(size_t)s * OUT_FEAT + k];
    }
    out[(size_t)n * OUT_FEAT + k] = acc + b2[k];
}

// ---------- launch ----------
extern "C" void kernel_launch(void* const* d_in, const int* in_sizes, int n_in,
                              void* d_out, int out_size, void* d_ws, size_t ws_size,
                              hipStream_t stream) {
    const float* X   = (const float*)d_in[0];
    const int*   ei  = (const int*)d_in[1];
    const float* W1  = (const float*)d_in[2];
    const float* as1 = (const float*)d_in[3];
    const float* ad1 = (const float*)d_in[4];
    const float* b1  = (const float*)d_in[5];
    const float* W2  = (const float*)d_in[6];
    const float* as2 = (const float*)d_in[7];
    const float* ad2 = (const float*)d_in[8];
    const float* b2  = (const float*)d_in[9];
    float* out = (float*)d_out;

    char* base = (char*)d_ws;
    auto carve = [&](size_t bytes) -> void* {
        void* p = (void*)base;
        base += (bytes + 255) & ~(size_t)255;
        return p;
    };
    float* p_src1 = (float*)carve(NH1 * IN_FEAT * 4);
    float* p_dst1 = (float*)carve(NH1 * IN_FEAT * 4);
    float* als1   = (float*)carve(N_NODES * NH1 * 4);
    float* ald1   = (float*)carve(N_NODES * NH1 * 4);
    float* als2   = (float*)carve(N_NODES * 4);
    float* ald2   = (float*)carve(N_NODES * 4);
    float* h2     = (float*)carve((size_t)M_PAD * OUT_FEAT * 4);                  // 8.0 MB
    int* counts   = (int*)carve(N_NODES * 4);
    int* cursor   = (int*)carve(N_NODES * 4);
    int* offs     = (int*)carve((N_NODES + 1) * 4);
    int* esrc     = (int*)carve(ET * 4);
    unsigned short* xaggb = (unsigned short*)carve((size_t)M_PAD * HSL * 2);      // 36 MB
    unsigned short* W1bt  = (unsigned short*)carve((size_t)NH1 * C1P * K1 * 2);   // 1.5 MB
    unsigned short* W2bt  = (unsigned short*)carve((size_t)N2P2 * KALL * 2);      // 1.7 MB
    float* h2p    = (float*)carve((size_t)NH1 * M_PAD * OUT_FEAT * 4);            // 64.3 MB

    // per-call init: only CSR counters (harness does not re-poison between replays)
    hipMemsetAsync(counts, 0, 2 * 40192, stream);  // counts + cursor (carve-aligned)

    // CSR + weight prep + layer-1 logits
    count_k<<<(ET + 255) / 256, 256, 0, stream>>>(ei, counts);
    scan_k<<<1, 1024, 0, stream>>>(counts, offs);
    scatter_k<<<(ET + 255) / 256, 256, 0, stream>>>(ei, offs, cursor, esrc);
    prep_w<<<(W1N + W2N + 255) / 256, 256, 0, stream>>>(W1, W2, W1bt, W2bt);
    pvec_k<<<(2 * NH1 * IN_FEAT + 255) / 256, 256, 0, stream>>>(W1, as1, ad1, p_src1, p_dst1);
    att1x<<<N_NODES, 512, 0, stream>>>(X, p_src1, p_dst1, als1, ald1);

    // Stage A: aggregated features (online softmax inside)
    agg1x<<<M_PAD / 8, 512, 0, stream>>>(X, als1, ald1, offs, esrc, xaggb);

    // fused GEMM1 (+bias+ELU) + GEMM2; 32-row waves, batched B loads, plain stores
    fused_gemm<<<dim3(M_PAD / 64, NH1), 256, 0, stream>>>(xaggb, W1bt, b1, W2bt, h2p);

    // reduce partials -> h2, fused layer-2 logits
    reduce_att2<<<M_PAD / 4, 256, 0, stream>>>(h2p, as2, ad2, h2, als2, ald2);

    // layer-2 aggregation (online softmax inside)
    agg2_csr<<<N_NODES, 256, 0, stream>>>(h2, als2, ald2, offs, esrc, b2, out);
}